// Round 3
// baseline (438.776 us; speedup 1.0000x reference)
//
#include <hip/hip_runtime.h>
#include <hip/hip_bf16.h>
#include <stdint.h>

#define B_ 2
#define T_ 2048
#define C_ 1024
#define H_ 16
#define D_ 64
#define F_ 4096
#define M_ (B_*T_)

typedef unsigned short ushort_t;
typedef __attribute__((ext_vector_type(8))) short short8;
typedef __attribute__((ext_vector_type(4))) float f32x4;

__device__ __forceinline__ float bf2f(ushort_t u) {
    union { unsigned u; float f; } c; c.u = ((unsigned)u) << 16; return c.f;
}
__device__ __forceinline__ ushort_t f2bf(float f) {
    union { float f; unsigned u; } c; c.f = f;
    unsigned u = c.u;
    unsigned r = (u + 0x7FFFu + ((u >> 16) & 1u)) >> 16;
    return (ushort_t)r;
}

__device__ __forceinline__ float fexp2(float x) { return __builtin_amdgcn_exp2f(x); }

// async global->LDS, 16B per lane. LDS dest = wave-uniform base + lane*16.
__device__ __forceinline__ void async16(void* lds, const void* g) {
    __builtin_amdgcn_global_load_lds(
        (const __attribute__((address_space(1))) unsigned int*)(uintptr_t)g,
        (__attribute__((address_space(3))) unsigned int*)(uintptr_t)lds,
        16, 0, 0);
}

// ---------------------------------------------------------------------------
// Batched transpose+cast of all 6 weights: out_bf16[c][r] = in_f32[r][c]
// ---------------------------------------------------------------------------
__global__ __launch_bounds__(256) void transpose_all_k(
    const float* __restrict__ Wq, const float* __restrict__ Wk,
    const float* __restrict__ Wv, const float* __restrict__ Wo,
    const float* __restrict__ W1, const float* __restrict__ W2,
    ushort_t* __restrict__ oq, ushort_t* __restrict__ ok,
    ushort_t* __restrict__ ov, ushort_t* __restrict__ oo,
    ushort_t* __restrict__ o1, ushort_t* __restrict__ o2) {
    __shared__ ushort_t tile[32][33];
    int id = blockIdx.x;
    const float* in; ushort_t* out; int R, Cc, bx, by;
    if (id < 4096) {
        int w = id >> 10, loc = id & 1023;
        in  = w == 0 ? Wq : w == 1 ? Wk : w == 2 ? Wv : Wo;
        out = w == 0 ? oq : w == 1 ? ok : w == 2 ? ov : oo;
        R = 1024; Cc = 1024; bx = loc & 31; by = loc >> 5;
    } else if (id < 8192) {
        int loc = id - 4096; in = W1; out = o1; R = 1024; Cc = 4096;
        bx = loc & 127; by = loc >> 7;
    } else {
        int loc = id - 8192; in = W2; out = o2; R = 4096; Cc = 1024;
        bx = loc & 31; by = loc >> 5;
    }
    int tx = threadIdx.x, ty = threadIdx.y;
    int x = bx * 32 + tx;
    int y0 = by * 32;
#pragma unroll
    for (int i = 0; i < 32; i += 8)
        tile[ty + i][tx] = f2bf(in[(size_t)(y0 + ty + i) * Cc + x]);
    __syncthreads();
    int x2 = y0 + tx;
    int y2 = bx * 32;
#pragma unroll
    for (int i = 0; i < 32; i += 8)
        out[(size_t)(y2 + ty + i) * R + x2] = tile[tx][ty + i];
}

// ---------------------------------------------------------------------------
// LayerNorm: fp32 input row of 1024, fp32 scale/shift, bf16 output.
// ---------------------------------------------------------------------------
__global__ __launch_bounds__(256) void ln_kernel(const float* __restrict__ xin,
                                                 const float* __restrict__ scale_p,
                                                 const float* __restrict__ shift_p,
                                                 ushort_t* __restrict__ out) {
    int row = blockIdx.x, t = threadIdx.x;
    int wv = t >> 6, lane = t & 63;
    const float* xr = xin + (size_t)row * 1024 + t * 4;
    float4 v = *(const float4*)xr;
    float f[4] = {v.x, v.y, v.z, v.w};
    float s = f[0] + f[1] + f[2] + f[3];
    float q = f[0]*f[0] + f[1]*f[1] + f[2]*f[2] + f[3]*f[3];
#pragma unroll
    for (int off = 1; off < 64; off <<= 1) {
        s += __shfl_xor(s, off, 64);
        q += __shfl_xor(q, off, 64);
    }
    __shared__ float sh_s[4], sh_q[4];
    if (lane == 0) { sh_s[wv] = s; sh_q[wv] = q; }
    __syncthreads();
    float S = sh_s[0] + sh_s[1] + sh_s[2] + sh_s[3];
    float Q = sh_q[0] + sh_q[1] + sh_q[2] + sh_q[3];
    float mean = S * (1.0f / 1024.0f);
    float var = Q * (1.0f / 1024.0f) - mean * mean;
    float rstd = rsqrtf(var + 1e-5f);
    float4 scv = *(const float4*)(scale_p + t * 4);
    float4 shv = *(const float4*)(shift_p + t * 4);
    ushort4 o;
    o.x = f2bf((f[0] - mean) * rstd * scv.x + shv.x);
    o.y = f2bf((f[1] - mean) * rstd * scv.y + shv.y);
    o.z = f2bf((f[2] - mean) * rstd * scv.z + shv.z);
    o.w = f2bf((f[3] - mean) * rstd * scv.w + shv.w);
    *(ushort4*)(out + (size_t)row * 1024 + t * 4) = o;
}

// ---------------------------------------------------------------------------
// prefill: out[i] = res[i] + bias[i mod 1024]  (f32, M*1024 elements)
// Seeds the split-K atomic accumulation target.
// ---------------------------------------------------------------------------
__global__ __launch_bounds__(256) void prefill_k(const float* __restrict__ res,
                                                 const float* __restrict__ bias,
                                                 float* __restrict__ out) {
    int i = blockIdx.x * 256 + threadIdx.x;   // float4 index
    const float4* r4 = (const float4*)res;
    float4* o4 = (float4*)out;
#pragma unroll
    for (int rep = 0; rep < 2; ++rep, i += 524288) {
        float4 rv = r4[i];
        float4 bv = *(const float4*)(bias + ((i << 2) & 1023));
        float4 ov;
        ov.x = rv.x + bv.x; ov.y = rv.y + bv.y;
        ov.z = rv.z + bv.z; ov.w = rv.w + bv.w;
        o4[i] = ov;
    }
}

// ---------------------------------------------------------------------------
// 256x256 8-phase GEMM (T2+T3+T4+T5): C[M,N] = A[M,K] @ Bt[N,K]^T (+ bias).
// 512 threads = 8 waves (2M x 4N), per-wave 128x64 output, BK=64.
// LDS [2 dbuf][2 ksub][256][32] per operand = 128 KiB, staged as 16 KB
// K-half units via global_load_lds(16B) with pre-swizzled global source
// (chunk ^= (row>>1)&3) -> bank-uniform ds_read_b128, linear DMA dest.
// Counted vmcnt(4) once per K-tile; stage issues run 1.5 tiles ahead into
// regions whose reads completed >=1 barrier earlier (race-audited).
// Split-K: blockIdx.z selects K-window [z*KC, (z+1)*KC); K = leading dim.
// EPI: 0 = split-K: atomicAdd f32 into prefilled out0 (no bias here)
//      2 = gelu, bf16 out0[M][N]
//      3 = QKV split: seg0/1 -> q,k row-major bf16 [.][1024]; seg2 -> v^T
// ---------------------------------------------------------------------------
template <int EPI>
__global__ __launch_bounds__(512) void gemm256(const ushort_t* __restrict__ A,
                                               const ushort_t* __restrict__ Bt,
                                               const float* __restrict__ b0,
                                               const float* __restrict__ b1,
                                               const float* __restrict__ b2,
                                               void* __restrict__ out0,
                                               void* __restrict__ out1,
                                               void* __restrict__ out2,
                                               int M, int N, int K, int KC) {
    __shared__ ushort_t As[2][2][256][32];   // [buf][ksub][row][k]
    __shared__ ushort_t Bs[2][2][256][32];
    const int t = threadIdx.x;
    const int wv = t >> 6, lane = t & 63, lo = lane & 15, hi = lane >> 4;
    const int wr = wv >> 2, wc = wv & 3;
    const int row0 = blockIdx.y * 256, col0 = blockIdx.x * 256;
    const int NT = KC >> 6;
    const size_t kb = (size_t)blockIdx.z * KC;
    const int swz8 = (hi ^ ((lo >> 1) & 3)) * 8;   // read-side chunk swizzle

    // staging source pointers (per-lane), pre-swizzled chunk within 32-elem row
    const ushort_t* Asrc[2];
    const ushort_t* Bsrc[2];
#pragma unroll
    for (int i = 0; i < 2; ++i) {
        int p = i * 512 + t, row = p >> 2, c4 = p & 3;
        int kof = (c4 ^ ((row >> 1) & 3)) * 8;
        Asrc[i] = A + (size_t)(row0 + row) * K + kb + kof;
        Bsrc[i] = Bt + (size_t)(col0 + row) * K + kb + kof;
    }

#define STG_A(KT, S) { const int _bf = (KT) & 1;                                   \
    _Pragma("unroll") for (int i = 0; i < 2; ++i)                                  \
        async16((char*)&As[_bf][S][0][0] + (size_t)(i * 512 + wv * 64) * 16,       \
                Asrc[i] + (KT) * 64 + (S) * 32); }
#define STG_B(KT, S) { const int _bf = (KT) & 1;                                   \
    _Pragma("unroll") for (int i = 0; i < 2; ++i)                                  \
        async16((char*)&Bs[_bf][S][0][0] + (size_t)(i * 512 + wv * 64) * 16,       \
                Bsrc[i] + (KT) * 64 + (S) * 32); }
#define LDA(KS) _Pragma("unroll") for (int mi = 0; mi < 8; ++mi)                   \
        af[mi] = *(const short8*)(&As[buf][KS][wr * 128 + mi * 16 + lo][swz8]);
#define LDB(KS, NH) _Pragma("unroll") for (int ni = 0; ni < 2; ++ni)               \
        bfv[ni] = *(const short8*)(&Bs[buf][KS][wc * 64 + ((NH) * 2 + ni) * 16 + lo][swz8]);
#define MMP(NH) __builtin_amdgcn_s_setprio(1);                                     \
    _Pragma("unroll") for (int mi = 0; mi < 8; ++mi) {                             \
        acc[mi][(NH) * 2 + 0] = __builtin_amdgcn_mfma_f32_16x16x32_bf16(           \
            af[mi], bfv[0], acc[mi][(NH) * 2 + 0], 0, 0, 0);                       \
        acc[mi][(NH) * 2 + 1] = __builtin_amdgcn_mfma_f32_16x16x32_bf16(           \
            af[mi], bfv[1], acc[mi][(NH) * 2 + 1], 0, 0, 0);                       \
    }                                                                              \
    __builtin_amdgcn_s_setprio(0);
#define ENDPH asm volatile("s_waitcnt lgkmcnt(0)" ::: "memory");                   \
    __builtin_amdgcn_sched_barrier(0); __builtin_amdgcn_s_barrier();

    f32x4 acc[8][4];
#pragma unroll
    for (int i = 0; i < 8; ++i)
#pragma unroll
        for (int j = 0; j < 4; ++j) acc[i][j] = (f32x4){0.f, 0.f, 0.f, 0.f};
    short8 af[8], bfv[2];

    // prologue: tile0 fully + tile1 K-half0 units; wait all of tile0 (8 loads)
    STG_A(0, 0) STG_B(0, 0) STG_A(0, 1) STG_B(0, 1)
    if (NT > 1) {
        STG_A(1, 0) STG_B(1, 0)
        asm volatile("s_waitcnt vmcnt(4)" ::: "memory");
    } else {
        asm volatile("s_waitcnt vmcnt(0)" ::: "memory");
    }
    __builtin_amdgcn_s_barrier();

    for (int kt = 0; kt < NT; ++kt) {
        const int buf = kt & 1;
        // ph0: ksub0, n-half0 (reads all A-ks0 + B-ks0-nh0)
        LDA(0) LDB(0, 0)
        if (kt + 1 < NT) STG_A(kt + 1, 1)
        MMP(0)
        ENDPH
        // ph1: ksub0, n-half1
        LDB(0, 1)
        if (kt + 1 < NT) STG_B(kt + 1, 1)
        MMP(1)
        ENDPH
        // ph2: ksub1, n-half0 (cur-buf ks0 regions free since ph0/ph1)
        LDA(1) LDB(1, 0)
        if (kt + 2 < NT) STG_A(kt + 2, 0)
        MMP(0)
        ENDPH
        // ph3: ksub1, n-half1 + tile-boundary counted wait
        LDB(1, 1)
        if (kt + 2 < NT) STG_B(kt + 2, 0)
        MMP(1)
        asm volatile("s_waitcnt lgkmcnt(0)" ::: "memory");
        if (kt + 2 < NT) {
            asm volatile("s_waitcnt vmcnt(4)" ::: "memory");
        } else if (kt + 1 < NT) {
            asm volatile("s_waitcnt vmcnt(0)" ::: "memory");
        }
        __builtin_amdgcn_sched_barrier(0);
        __builtin_amdgcn_s_barrier();
    }

#undef STG_A
#undef STG_B
#undef LDA
#undef LDB
#undef MMP
#undef ENDPH

    if (EPI == 0) {
        float* po = (float*)out0;
#pragma unroll
        for (int ni = 0; ni < 4; ++ni) {
            const int n = col0 + wc * 64 + ni * 16 + lo;
#pragma unroll
            for (int mi = 0; mi < 8; ++mi) {
#pragma unroll
                for (int r = 0; r < 4; ++r) {
                    const int m = row0 + wr * 128 + mi * 16 + 4 * hi + r;
                    atomicAdd(po + (size_t)m * N + n, acc[mi][ni][r]);
                }
            }
        }
        return;
    }

#pragma unroll
    for (int ni = 0; ni < 4; ++ni) {
        const int n = col0 + wc * 64 + ni * 16 + lo;
        float bn;
        ushort_t* obf = nullptr;
        int coln = n, seg = 0;
        if (EPI == 3) {
            seg = n >> 10; coln = n & 1023;
            bn = (seg == 0 ? b0 : seg == 1 ? b1 : b2)[coln];
            obf = (ushort_t*)(seg == 0 ? out0 : out1);
        } else {
            bn = b0[n];
        }
#pragma unroll
        for (int mi = 0; mi < 8; ++mi) {
            if (EPI == 3 && seg == 2) {
                const int m0 = row0 + wr * 128 + mi * 16 + 4 * hi;
                ushort4 pk;
                pk.x = f2bf(acc[mi][ni][0] + bn);
                pk.y = f2bf(acc[mi][ni][1] + bn);
                pk.z = f2bf(acc[mi][ni][2] + bn);
                pk.w = f2bf(acc[mi][ni][3] + bn);
                *(ushort4*)((ushort_t*)out2 + (size_t)coln * M + m0) = pk;
            } else {
#pragma unroll
                for (int r = 0; r < 4; ++r) {
                    const int m = row0 + wr * 128 + mi * 16 + 4 * hi + r;
                    float v = acc[mi][ni][r] + bn;
                    if (EPI == 2) {
                        v = 0.5f * v * (1.0f + erff(v * 0.70710678118654752f));
                        ((ushort_t*)out0)[(size_t)m * N + n] = f2bf(v);
                    } else {
                        obf[(size_t)m * 1024 + coln] = f2bf(v);
                    }
                }
            }
        }
    }
}

// ---------------------------------------------------------------------------
// Causal flash attention: 64-row q-tiles, grid 1024 (32 qt x 32 bh),
// longest strips dispatched first (qt = 31 - id/32) so the 32-tile critical
// block starts at t=0 and every CU holds 4 blocks (LDS = 40960 exactly).
// P spill: per-wave [16][64] tile, XOR chunk swizzle (chunk ^= lo&7),
// packed ds_write_b64 (4 writes/wave-tile instead of 32 scalar b16).
// ---------------------------------------------------------------------------
__global__ __launch_bounds__(256) void attn_kernel(const ushort_t* __restrict__ q,
                                                   const ushort_t* __restrict__ k,
                                                   const ushort_t* __restrict__ vt,
                                                   ushort_t* __restrict__ ctx) {
    __shared__ ushort_t Ks[2][64 * 64];   // [buf][key][d], col-chunk swizzled
    __shared__ ushort_t VTs[2][64 * 64];  // [buf][d][key], col-chunk swizzled
    __shared__ ushort_t Ps[4][16 * 64];   // [wave][qrow][key], XOR-swizzled chunks

    const int t = threadIdx.x;
    const int wv = t >> 6, lane = t & 63, lo = lane & 15, hi = lane >> 4;
    const int id = blockIdx.x;             // 1024
    const int qt = 31 - (id >> 5);         // longest-first
    const int bh = id & 31, b = bh >> 4, h = bh & 15;
    const int q0 = qt * 64;
    const size_t headoff = (size_t)h * 64;
    const size_t rowbase = (size_t)b * T_ * 1024;
    const ushort_t* vbase = vt + headoff * (size_t)M_ + (size_t)b * T_;

    short8 qf[2];
    {
        const ushort_t* qp = q + rowbase + (size_t)(q0 + wv * 16 + lo) * 1024 + headoff;
        qf[0] = *(const short8*)(qp + hi * 8);
        qf[1] = *(const short8*)(qp + 32 + hi * 8);
    }

    float m_r = -1e30f, l_r = 0.f;
    f32x4 o_acc[4];
#pragma unroll
    for (int dt = 0; dt < 4; ++dt) o_acc[dt] = (f32x4){0.f, 0.f, 0.f, 0.f};

    const float SC = 0.18033688011112042f;  // 0.125 * log2(e)
    const f32x4 NEG4 = (f32x4){-1e30f, -1e30f, -1e30f, -1e30f};

    auto stage = [&](int bb, int kt) {
        const int k0s = kt * 64;
#pragma unroll
        for (int i = 0; i < 2; ++i) {
            int c = i * 256 + t;
            int row = c >> 3, c8 = c & 7;
            int gsw = c8 ^ (row & 7);
            async16((char*)&Ks[bb][0] + (size_t)(i * 256 + wv * 64) * 16,
                    k + rowbase + (size_t)(k0s + row) * 1024 + headoff + gsw * 8);
            async16((char*)&VTs[bb][0] + (size_t)(i * 256 + wv * 64) * 16,
                    vbase + (size_t)row * M_ + k0s + gsw * 8);
        }
    };

    ushort_t* Pw = Ps[wv];
    const int psw = lo & 7;

    stage(0, 0);
    for (int kt = 0; kt <= qt; ++kt) {
        const int bb = kt & 1;
        const int k0 = kt * 64;
        __syncthreads();
        if (kt < qt) stage(bb ^ 1, kt + 1);

        const int diff = q0 + wv * 16 - k0;   // >= 0 always (kt <= qt)
        const int cmax = diff >= 48 ? 3 : (diff >> 4);

        f32x4 sacc[4];
#pragma unroll
        for (int kt16 = 0; kt16 < 4; ++kt16) {
            if (kt16 <= cmax) {
                int row = kt16 * 16 + lo, sw = row & 7;
                short8 kf0 = *(const short8*)(&Ks[bb][0] + row * 64 + (hi ^ sw) * 8);
                short8 kf1 = *(const short8*)(&Ks[bb][0] + row * 64 + ((4 + hi) ^ sw) * 8);
                f32x4 z = (f32x4){0.f, 0.f, 0.f, 0.f};
                z = __builtin_amdgcn_mfma_f32_16x16x32_bf16(kf0, qf[0], z, 0, 0, 0);
                z = __builtin_amdgcn_mfma_f32_16x16x32_bf16(kf1, qf[1], z, 0, 0, 0);
#pragma unroll
                for (int r = 0; r < 4; ++r) sacc[kt16][r] = z[r] * SC;
            } else {
                sacc[kt16] = NEG4;
            }
        }
        if (diff < 64) {  // diagonal subtile: element mask key > qrow
            const int qrow = diff + lo;
#pragma unroll
            for (int r = 0; r < 4; ++r) {
                int key = cmax * 16 + 4 * hi + r;
                if (key > qrow) sacc[cmax][r] = -1e30f;
            }
        }

        // ---- online softmax (rows = lo), packed P spill ----
        float mx = -1e30f;
#pragma unroll
        for (int kt16 = 0; kt16 < 4; ++kt16)
#pragma unroll
            for (int r = 0; r < 4; ++r) mx = fmaxf(mx, sacc[kt16][r]);
        mx = fmaxf(mx, __shfl_xor(mx, 16, 64));
        mx = fmaxf(mx, __shfl_xor(mx, 32, 64));
        float mnew = fmaxf(m_r, mx);
        float alpha = fexp2(m_r - mnew);
        m_r = mnew;
        float rs = 0.f;
#pragma unroll
        for (int kt16 = 0; kt16 < 4; ++kt16) {
            float p0 = fexp2(sacc[kt16][0] - mnew);
            float p1 = fexp2(sacc[kt16][1] - mnew);
            float p2 = fexp2(sacc[kt16][2] - mnew);
            float p3 = fexp2(sacc[kt16][3] - mnew);
            rs += p0 + p1 + p2 + p3;
            ushort4 pk;
            pk.x = f2bf(p0); pk.y = f2bf(p1); pk.z = f2bf(p2); pk.w = f2bf(p3);
            // key s = kt16*16 + 4*hi + r -> chunk 2*kt16 + (hi>>1), offset 4*(hi&1)
            *(ushort4*)(Pw + lo * 64 + (((2 * kt16 + (hi >> 1)) ^ psw) << 3) + 4 * (hi & 1)) = pk;
        }
        rs += __shfl_xor(rs, 16, 64);
        rs += __shfl_xor(rs, 32, 64);
        l_r = l_r * alpha + rs;
#pragma unroll
        for (int r = 0; r < 4; ++r) {
            float ab = __shfl(alpha, 4 * hi + r, 64);
#pragma unroll
            for (int dt = 0; dt < 4; ++dt) o_acc[dt][r] *= ab;
        }

        // ---- read P fragments back (same-wave LDS, in-order) ----
        short8 pf0 = *(const short8*)(Pw + lo * 64 + ((hi ^ psw) << 3));
        short8 pf1 = *(const short8*)(Pw + lo * 64 + (((4 + hi) ^ psw) << 3));

        // ---- PV ----
#pragma unroll
        for (int dt = 0; dt < 4; ++dt) {
            int row = dt * 16 + lo, sw = row & 7;
            short8 vf0 = *(const short8*)(&VTs[bb][0] + row * 64 + (hi ^ sw) * 8);
            short8 vf1 = *(const short8*)(&VTs[bb][0] + row * 64 + ((4 + hi) ^ sw) * 8);
            o_acc[dt] = __builtin_amdgcn_mfma_f32_16x16x32_bf16(pf0, vf0, o_acc[dt], 0, 0, 0);
            o_acc[dt] = __builtin_amdgcn_mfma_f32_16x16x32_bf16(pf1, vf1, o_acc[dt], 0, 0, 0);
        }
    }

#pragma unroll
    for (int r = 0; r < 4; ++r) {
        float lb = __shfl(l_r, 4 * hi + r, 64);
        float inv = 1.0f / lb;
        size_t row = rowbase + (size_t)(q0 + wv * 16 + 4 * hi + r) * 1024 + headoff;
#pragma unroll
        for (int dt = 0; dt < 4; ++dt)
            ctx[row + dt * 16 + lo] = f2bf(o_acc[dt][r] * inv);
    }
}

// ---------------------------------------------------------------------------
extern "C" void kernel_launch(void* const* d_in, const int* in_sizes, int n_in,
                              void* d_out, int out_size, void* d_ws, size_t ws_size,
                              hipStream_t stream) {
    (void)in_sizes; (void)n_in; (void)out_size; (void)ws_size;
    const float* x    = (const float*)d_in[0];
    const float* Wq   = (const float*)d_in[1];
    const float* bq   = (const float*)d_in[2];
    const float* Wk   = (const float*)d_in[3];
    const float* bk   = (const float*)d_in[4];
    const float* Wv   = (const float*)d_in[5];
    const float* bv   = (const float*)d_in[6];
    const float* Wo   = (const float*)d_in[7];
    const float* bo   = (const float*)d_in[8];
    const float* W1   = (const float*)d_in[9];
    const float* b1   = (const float*)d_in[10];
    const float* W2   = (const float*)d_in[11];
    const float* b2   = (const float*)d_in[12];
    const float* ln1s = (const float*)d_in[13];
    const float* ln1b = (const float*)d_in[14];
    const float* ln2s = (const float*)d_in[15];
    const float* ln2b = (const float*)d_in[16];

    char* ws = (char*)d_ws;
    const size_t MB = 1024 * 1024;
    ushort_t* wqkv = (ushort_t*)(ws + 0 * MB);   // wtq|wtk|wtv contiguous [3072][1024]
    ushort_t* wtq  = (ushort_t*)(ws + 0 * MB);
    ushort_t* wtk  = (ushort_t*)(ws + 2 * MB);
    ushort_t* wtv  = (ushort_t*)(ws + 4 * MB);
    ushort_t* wto  = (ushort_t*)(ws + 6 * MB);
    ushort_t* wt1  = (ushort_t*)(ws + 8 * MB);   // 8MB (4096x1024)
    ushort_t* wt2  = (ushort_t*)(ws + 16 * MB);  // 8MB (1024x4096)
    ushort_t* hbuf = (ushort_t*)(ws + 24 * MB);  // 8MB
    ushort_t* qb_  = (ushort_t*)(ws + 32 * MB);  // 8MB
    ushort_t* kb_  = (ushort_t*)(ws + 40 * MB);  // 8MB
    ushort_t* ctx  = (ushort_t*)(ws + 56 * MB);  // 8MB
    ushort_t* hid  = (ushort_t*)(ws + 32 * MB);  // 32MB, reuses q/k/ctx post-attn
    float*    x1   = (float*)(ws + 64 * MB);     // 16MB fp32 (written after attn)
    ushort_t* vtb  = (ushort_t*)(ws + 64 * MB);  // 8MB [1024][4096], dead after attn

    transpose_all_k<<<12288, dim3(32, 8), 0, stream>>>(Wq, Wk, Wv, Wo, W1, W2,
                                                       wtq, wtk, wtv, wto, wt1, wt2);

    ln_kernel<<<4096, 256, 0, stream>>>(x, ln1s, ln1b, hbuf);

    // fused QKV (256^2 8-phase); seg2 writes v^T directly into vtb [1024][4096]
    gemm256<3><<<dim3(12, 16, 1), 512, 0, stream>>>(hbuf, wqkv, bq, bk, bv,
                                                    qb_, kb_, vtb, 4096, 3072, 1024, 1024);

    attn_kernel<<<1024, 256, 0, stream>>>(qb_, kb_, vtb, ctx);

    // Wo projection, split-K=4 atomic: x1 = x + bo + ctx @ Wo^T
    prefill_k<<<2048, 256, 0, stream>>>(x, bo, x1);
    gemm256<0><<<dim3(4, 16, 4), 512, 0, stream>>>(ctx, wto, nullptr, nullptr, nullptr,
                                                   x1, nullptr, nullptr, 4096, 1024, 1024, 256);

    ln_kernel<<<4096, 256, 0, stream>>>(x1, ln2s, ln2b, hbuf);

    // FF1 (256^2 8-phase, gelu epilogue)
    gemm256<2><<<dim3(16, 16, 1), 512, 0, stream>>>(hbuf, wt1, b1, nullptr, nullptr,
                                                    hid, nullptr, nullptr, 4096, 4096, 1024, 1024);

    // FF2, split-K=4 atomic: d_out = x1 + b2 + hid @ W2^T
    prefill_k<<<2048, 256, 0, stream>>>(x1, b2, (float*)d_out);
    gemm256<0><<<dim3(4, 16, 4), 512, 0, stream>>>(hid, wt2, nullptr, nullptr, nullptr,
                                                   d_out, nullptr, nullptr, 4096, 1024, 4096, 1024);
}

// Round 4
// 399.667 us; speedup vs baseline: 1.0979x; 1.0979x over previous
//
#include <hip/hip_runtime.h>
#include <hip/hip_bf16.h>
#include <stdint.h>

#define B_ 2
#define T_ 2048
#define C_ 1024
#define H_ 16
#define D_ 64
#define F_ 4096
#define M_ (B_*T_)

typedef unsigned short ushort_t;
typedef __attribute__((ext_vector_type(8))) short short8;
typedef __attribute__((ext_vector_type(4))) float f32x4;

__device__ __forceinline__ float bf2f(ushort_t u) {
    union { unsigned u; float f; } c; c.u = ((unsigned)u) << 16; return c.f;
}
__device__ __forceinline__ ushort_t f2bf(float f) {
    union { float f; unsigned u; } c; c.f = f;
    unsigned u = c.u;
    unsigned r = (u + 0x7FFFu + ((u >> 16) & 1u)) >> 16;
    return (ushort_t)r;
}

__device__ __forceinline__ float fexp2(float x) { return __builtin_amdgcn_exp2f(x); }

// async global->LDS, 16B per lane. LDS dest = wave-uniform base + lane*16.
__device__ __forceinline__ void async16(void* lds, const void* g) {
    __builtin_amdgcn_global_load_lds(
        (const __attribute__((address_space(1))) unsigned int*)(uintptr_t)g,
        (__attribute__((address_space(3))) unsigned int*)(uintptr_t)lds,
        16, 0, 0);
}

// ---------------------------------------------------------------------------
// Batched transpose+cast of all 6 weights: out_bf16[c][r] = in_f32[r][c]
// ---------------------------------------------------------------------------
__global__ __launch_bounds__(256) void transpose_all_k(
    const float* __restrict__ Wq, const float* __restrict__ Wk,
    const float* __restrict__ Wv, const float* __restrict__ Wo,
    const float* __restrict__ W1, const float* __restrict__ W2,
    ushort_t* __restrict__ oq, ushort_t* __restrict__ ok,
    ushort_t* __restrict__ ov, ushort_t* __restrict__ oo,
    ushort_t* __restrict__ o1, ushort_t* __restrict__ o2) {
    __shared__ ushort_t tile[32][33];
    int id = blockIdx.x;
    const float* in; ushort_t* out; int R, Cc, bx, by;
    if (id < 4096) {
        int w = id >> 10, loc = id & 1023;
        in  = w == 0 ? Wq : w == 1 ? Wk : w == 2 ? Wv : Wo;
        out = w == 0 ? oq : w == 1 ? ok : w == 2 ? ov : oo;
        R = 1024; Cc = 1024; bx = loc & 31; by = loc >> 5;
    } else if (id < 8192) {
        int loc = id - 4096; in = W1; out = o1; R = 1024; Cc = 4096;
        bx = loc & 127; by = loc >> 7;
    } else {
        int loc = id - 8192; in = W2; out = o2; R = 4096; Cc = 1024;
        bx = loc & 31; by = loc >> 5;
    }
    int tx = threadIdx.x, ty = threadIdx.y;
    int x = bx * 32 + tx;
    int y0 = by * 32;
#pragma unroll
    for (int i = 0; i < 32; i += 8)
        tile[ty + i][tx] = f2bf(in[(size_t)(y0 + ty + i) * Cc + x]);
    __syncthreads();
    int x2 = y0 + tx;
    int y2 = bx * 32;
#pragma unroll
    for (int i = 0; i < 32; i += 8)
        out[(size_t)(y2 + ty + i) * R + x2] = tile[tx][ty + i];
}

// ---------------------------------------------------------------------------
// LayerNorm: fp32 input row of 1024, fp32 scale/shift, bf16 output.
// ---------------------------------------------------------------------------
__global__ __launch_bounds__(256) void ln_kernel(const float* __restrict__ xin,
                                                 const float* __restrict__ scale_p,
                                                 const float* __restrict__ shift_p,
                                                 ushort_t* __restrict__ out) {
    int row = blockIdx.x, t = threadIdx.x;
    int wv = t >> 6, lane = t & 63;
    const float* xr = xin + (size_t)row * 1024 + t * 4;
    float4 v = *(const float4*)xr;
    float f[4] = {v.x, v.y, v.z, v.w};
    float s = f[0] + f[1] + f[2] + f[3];
    float q = f[0]*f[0] + f[1]*f[1] + f[2]*f[2] + f[3]*f[3];
#pragma unroll
    for (int off = 1; off < 64; off <<= 1) {
        s += __shfl_xor(s, off, 64);
        q += __shfl_xor(q, off, 64);
    }
    __shared__ float sh_s[4], sh_q[4];
    if (lane == 0) { sh_s[wv] = s; sh_q[wv] = q; }
    __syncthreads();
    float S = sh_s[0] + sh_s[1] + sh_s[2] + sh_s[3];
    float Q = sh_q[0] + sh_q[1] + sh_q[2] + sh_q[3];
    float mean = S * (1.0f / 1024.0f);
    float var = Q * (1.0f / 1024.0f) - mean * mean;
    float rstd = rsqrtf(var + 1e-5f);
    float4 scv = *(const float4*)(scale_p + t * 4);
    float4 shv = *(const float4*)(shift_p + t * 4);
    ushort4 o;
    o.x = f2bf((f[0] - mean) * rstd * scv.x + shv.x);
    o.y = f2bf((f[1] - mean) * rstd * scv.y + shv.y);
    o.z = f2bf((f[2] - mean) * rstd * scv.z + shv.z);
    o.w = f2bf((f[3] - mean) * rstd * scv.w + shv.w);
    *(ushort4*)(out + (size_t)row * 1024 + t * 4) = o;
}

// ---------------------------------------------------------------------------
// GEMM (m97 structure, async global->LDS staging):
// C[M,N] = A[M,K](bf16) @ Bt[N,K](bf16)^T + bias(f32)
// Tile (32*MT) x 128, BK=32, 4 waves 2x2.  Used for Wo / FF2 (N=1024).
// EPI: 1 = +f32 residual, f32 out; 2 = gelu, bf16 out
// ---------------------------------------------------------------------------
template <int MT, int EPI>
__global__ __launch_bounds__(256) void gemm_bt(const ushort_t* __restrict__ A,
                                               const ushort_t* __restrict__ Bt,
                                               const float* __restrict__ b0,
                                               const float* __restrict__ res,
                                               void* __restrict__ out0,
                                               int M, int N, int K) {
    __shared__ ushort_t As[32 * MT * 32];
    __shared__ ushort_t Bs[128 * 32];
    const int t = threadIdx.x;
    const int wv = t >> 6, lane = t & 63, lo = lane & 15, hi = lane >> 4;
    const int wr = wv >> 1, wc = wv & 1;
    const int mb = blockIdx.y, nb = blockIdx.x;

    f32x4 acc[MT][4];
#pragma unroll
    for (int i = 0; i < MT; ++i)
#pragma unroll
        for (int j = 0; j < 4; ++j) acc[i][j] = (f32x4){0.f, 0.f, 0.f, 0.f};

    for (int k0 = 0; k0 < K; k0 += 32) {
#pragma unroll
        for (int i = 0; i < MT / 2; ++i) {
            int c = i * 256 + t;
            int row = c >> 2, kc = c & 3;
            async16((char*)As + (size_t)(i * 256 + wv * 64) * 16,
                    A + (size_t)(mb * 32 * MT + row) * K + k0 + kc * 8);
        }
#pragma unroll
        for (int i = 0; i < 2; ++i) {
            int c = i * 256 + t;
            int row = c >> 2, kc = c & 3;
            async16((char*)Bs + (size_t)(i * 256 + wv * 64) * 16,
                    Bt + (size_t)(nb * 128 + row) * K + k0 + kc * 8);
        }
        __syncthreads();

        short8 af[MT], bfr[4];
#pragma unroll
        for (int mi = 0; mi < MT; ++mi)
            af[mi] = *(const short8*)(As + (wr * 16 * MT + mi * 16 + lo) * 32 + hi * 8);
#pragma unroll
        for (int ni = 0; ni < 4; ++ni)
            bfr[ni] = *(const short8*)(Bs + (wc * 64 + ni * 16 + lo) * 32 + hi * 8);
#pragma unroll
        for (int mi = 0; mi < MT; ++mi)
#pragma unroll
            for (int ni = 0; ni < 4; ++ni)
                acc[mi][ni] = __builtin_amdgcn_mfma_f32_16x16x32_bf16(
                    af[mi], bfr[ni], acc[mi][ni], 0, 0, 0);
        __syncthreads();
    }

#pragma unroll
    for (int ni = 0; ni < 4; ++ni) {
        int n = nb * 128 + wc * 64 + ni * 16 + lo;
        float bn = b0[n];
#pragma unroll
        for (int mi = 0; mi < MT; ++mi) {
#pragma unroll
            for (int r = 0; r < 4; ++r) {
                int m = mb * 32 * MT + wr * 16 * MT + mi * 16 + 4 * hi + r;
                float v = acc[mi][ni][r] + bn;
                if (EPI == 1) {
                    size_t idx = (size_t)m * N + n;
                    ((float*)out0)[idx] = v + res[idx];
                } else {
                    v = 0.5f * v * (1.0f + erff(v * 0.70710678118654752f));
                    ((ushort_t*)out0)[(size_t)m * N + n] = f2bf(v);
                }
            }
        }
    }
}

// ---------------------------------------------------------------------------
// 256x256 8-phase GEMM, m201 double-barrier phase form:
//   phase = { ds_read issue ; stage issue ; s_barrier ; lgkmcnt(0) ;
//             sched_barrier ; setprio(1) 16xMFMA setprio(0) ; s_barrier }
// so a wave's ds_read latency overlaps other waves' MFMA + barrier skew.
// 512 threads = 8 waves (2M x 4N), per-wave 128x64 output, BK=64.
// LDS [2 dbuf][2 ksub][256][32] per operand = 128 KiB; gload_lds(16B) with
// pre-swizzled global source; counted vmcnt(4) once per K-tile (ph3 end).
// Region audit: a staged region's readers all retire >=1 barrier before the
// overwriting stage issues (unchanged from prior rounds; barriers added).
// EPI: 2 = gelu, bf16 out0[M][N]
//      3 = QKV split: seg0/1 -> q,k row-major bf16 [.][1024]; seg2 -> v^T
// ---------------------------------------------------------------------------
template <int EPI>
__global__ __launch_bounds__(512) void gemm256(const ushort_t* __restrict__ A,
                                               const ushort_t* __restrict__ Bt,
                                               const float* __restrict__ b0,
                                               const float* __restrict__ b1,
                                               const float* __restrict__ b2,
                                               void* __restrict__ out0,
                                               void* __restrict__ out1,
                                               void* __restrict__ out2,
                                               int M, int N, int K) {
    __shared__ ushort_t As[2][2][256][32];   // [buf][ksub][row][k]
    __shared__ ushort_t Bs[2][2][256][32];
    const int t = threadIdx.x;
    const int wv = t >> 6, lane = t & 63, lo = lane & 15, hi = lane >> 4;
    const int wr = wv >> 2, wc = wv & 3;
    const int row0 = blockIdx.y * 256, col0 = blockIdx.x * 256;
    const int NT = K >> 6;
    const int swz8 = (hi ^ ((lo >> 1) & 3)) * 8;   // read-side chunk swizzle

    // staging source pointers (per-lane), pre-swizzled chunk within 32-elem row
    const ushort_t* Asrc[2];
    const ushort_t* Bsrc[2];
#pragma unroll
    for (int i = 0; i < 2; ++i) {
        int p = i * 512 + t, row = p >> 2, c4 = p & 3;
        int kof = (c4 ^ ((row >> 1) & 3)) * 8;
        Asrc[i] = A + (size_t)(row0 + row) * K + kof;
        Bsrc[i] = Bt + (size_t)(col0 + row) * K + kof;
    }

#define STG_A(KT, S) { const int _bf = (KT) & 1;                                   \
    _Pragma("unroll") for (int i = 0; i < 2; ++i)                                  \
        async16((char*)&As[_bf][S][0][0] + (size_t)(i * 512 + wv * 64) * 16,       \
                Asrc[i] + (KT) * 64 + (S) * 32); }
#define STG_B(KT, S) { const int _bf = (KT) & 1;                                   \
    _Pragma("unroll") for (int i = 0; i < 2; ++i)                                  \
        async16((char*)&Bs[_bf][S][0][0] + (size_t)(i * 512 + wv * 64) * 16,       \
                Bsrc[i] + (KT) * 64 + (S) * 32); }
#define LDA(KS) _Pragma("unroll") for (int mi = 0; mi < 8; ++mi)                   \
        af[mi] = *(const short8*)(&As[buf][KS][wr * 128 + mi * 16 + lo][swz8]);
#define LDB(KS, NH) _Pragma("unroll") for (int ni = 0; ni < 2; ++ni)               \
        bfv[ni] = *(const short8*)(&Bs[buf][KS][wc * 64 + ((NH) * 2 + ni) * 16 + lo][swz8]);
#define MMP(NH) __builtin_amdgcn_s_setprio(1);                                     \
    _Pragma("unroll") for (int mi = 0; mi < 8; ++mi) {                             \
        acc[mi][(NH) * 2 + 0] = __builtin_amdgcn_mfma_f32_16x16x32_bf16(           \
            af[mi], bfv[0], acc[mi][(NH) * 2 + 0], 0, 0, 0);                       \
        acc[mi][(NH) * 2 + 1] = __builtin_amdgcn_mfma_f32_16x16x32_bf16(           \
            af[mi], bfv[1], acc[mi][(NH) * 2 + 1], 0, 0, 0);                       \
    }                                                                              \
    __builtin_amdgcn_s_setprio(0);
// barrier -> own-reads-done -> fence (rule #18) -> MFMA -> barrier
#define PH_MM(NH) __builtin_amdgcn_s_barrier();                                    \
    asm volatile("s_waitcnt lgkmcnt(0)" ::: "memory");                             \
    __builtin_amdgcn_sched_barrier(0);                                             \
    MMP(NH)                                                                        \
    __builtin_amdgcn_s_barrier();

    f32x4 acc[8][4];
#pragma unroll
    for (int i = 0; i < 8; ++i)
#pragma unroll
        for (int j = 0; j < 4; ++j) acc[i][j] = (f32x4){0.f, 0.f, 0.f, 0.f};
    short8 af[8], bfv[2];

    // prologue: tile0 fully + tile1 K-half0 units; wait all of tile0 (8 loads)
    STG_A(0, 0) STG_B(0, 0) STG_A(0, 1) STG_B(0, 1)
    if (NT > 1) {
        STG_A(1, 0) STG_B(1, 0)
        asm volatile("s_waitcnt vmcnt(4)" ::: "memory");
    } else {
        asm volatile("s_waitcnt vmcnt(0)" ::: "memory");
    }
    __builtin_amdgcn_s_barrier();

    for (int kt = 0; kt < NT; ++kt) {
        const int buf = kt & 1;
        // ph0: reads (A-ks0 + B-ks0-nh0) + stage, then barrier'd MFMA
        LDA(0) LDB(0, 0)
        if (kt + 1 < NT) STG_A(kt + 1, 1)
        PH_MM(0)
        // ph1
        LDB(0, 1)
        if (kt + 1 < NT) STG_B(kt + 1, 1)
        PH_MM(1)
        // ph2 (cur-buf ks0 regions free: all readers retired at ph1 barriers)
        LDA(1) LDB(1, 0)
        if (kt + 2 < NT) STG_A(kt + 2, 0)
        PH_MM(0)
        // ph3 + tile-boundary counted wait before final barrier
        LDB(1, 1)
        if (kt + 2 < NT) STG_B(kt + 2, 0)
        __builtin_amdgcn_s_barrier();
        asm volatile("s_waitcnt lgkmcnt(0)" ::: "memory");
        __builtin_amdgcn_sched_barrier(0);
        MMP(1)
        if (kt + 2 < NT) {
            asm volatile("s_waitcnt vmcnt(4)" ::: "memory");
        } else if (kt + 1 < NT) {
            asm volatile("s_waitcnt vmcnt(0)" ::: "memory");
        }
        __builtin_amdgcn_sched_barrier(0);
        __builtin_amdgcn_s_barrier();
    }

#undef STG_A
#undef STG_B
#undef LDA
#undef LDB
#undef MMP
#undef PH_MM

#pragma unroll
    for (int ni = 0; ni < 4; ++ni) {
        const int n = col0 + wc * 64 + ni * 16 + lo;
        float bn;
        ushort_t* obf = nullptr;
        int coln = n, seg = 0;
        if (EPI == 3) {
            seg = n >> 10; coln = n & 1023;
            bn = (seg == 0 ? b0 : seg == 1 ? b1 : b2)[coln];
            obf = (ushort_t*)(seg == 0 ? out0 : out1);
        } else {
            bn = b0[n];
        }
#pragma unroll
        for (int mi = 0; mi < 8; ++mi) {
            if (EPI == 3 && seg == 2) {
                const int m0 = row0 + wr * 128 + mi * 16 + 4 * hi;
                ushort4 pk;
                pk.x = f2bf(acc[mi][ni][0] + bn);
                pk.y = f2bf(acc[mi][ni][1] + bn);
                pk.z = f2bf(acc[mi][ni][2] + bn);
                pk.w = f2bf(acc[mi][ni][3] + bn);
                *(ushort4*)((ushort_t*)out2 + (size_t)coln * M + m0) = pk;
            } else {
#pragma unroll
                for (int r = 0; r < 4; ++r) {
                    const int m = row0 + wr * 128 + mi * 16 + 4 * hi + r;
                    float v = acc[mi][ni][r] + bn;
                    if (EPI == 2) {
                        v = 0.5f * v * (1.0f + erff(v * 0.70710678118654752f));
                        ((ushort_t*)out0)[(size_t)m * N + n] = f2bf(v);
                    } else {
                        obf[(size_t)m * 1024 + coln] = f2bf(v);
                    }
                }
            }
        }
    }
}

// ---------------------------------------------------------------------------
// Causal flash attention: 64-row q-tiles, grid 1024 (32 qt x 32 bh),
// longest strips dispatched first; 4 blocks/CU (LDS = 40960).
// ---------------------------------------------------------------------------
__global__ __launch_bounds__(256) void attn_kernel(const ushort_t* __restrict__ q,
                                                   const ushort_t* __restrict__ k,
                                                   const ushort_t* __restrict__ vt,
                                                   ushort_t* __restrict__ ctx) {
    __shared__ ushort_t Ks[2][64 * 64];   // [buf][key][d], col-chunk swizzled
    __shared__ ushort_t VTs[2][64 * 64];  // [buf][d][key], col-chunk swizzled
    __shared__ ushort_t Ps[4][16 * 64];   // [wave][qrow][key], XOR-swizzled chunks

    const int t = threadIdx.x;
    const int wv = t >> 6, lane = t & 63, lo = lane & 15, hi = lane >> 4;
    const int id = blockIdx.x;             // 1024
    const int qt = 31 - (id >> 5);         // longest-first
    const int bh = id & 31, b = bh >> 4, h = bh & 15;
    const int q0 = qt * 64;
    const size_t headoff = (size_t)h * 64;
    const size_t rowbase = (size_t)b * T_ * 1024;
    const ushort_t* vbase = vt + headoff * (size_t)M_ + (size_t)b * T_;

    short8 qf[2];
    {
        const ushort_t* qp = q + rowbase + (size_t)(q0 + wv * 16 + lo) * 1024 + headoff;
        qf[0] = *(const short8*)(qp + hi * 8);
        qf[1] = *(const short8*)(qp + 32 + hi * 8);
    }

    float m_r = -1e30f, l_r = 0.f;
    f32x4 o_acc[4];
#pragma unroll
    for (int dt = 0; dt < 4; ++dt) o_acc[dt] = (f32x4){0.f, 0.f, 0.f, 0.f};

    const float SC = 0.18033688011112042f;  // 0.125 * log2(e)
    const f32x4 NEG4 = (f32x4){-1e30f, -1e30f, -1e30f, -1e30f};

    auto stage = [&](int bb, int kt) {
        const int k0s = kt * 64;
#pragma unroll
        for (int i = 0; i < 2; ++i) {
            int c = i * 256 + t;
            int row = c >> 3, c8 = c & 7;
            int gsw = c8 ^ (row & 7);
            async16((char*)&Ks[bb][0] + (size_t)(i * 256 + wv * 64) * 16,
                    k + rowbase + (size_t)(k0s + row) * 1024 + headoff + gsw * 8);
            async16((char*)&VTs[bb][0] + (size_t)(i * 256 + wv * 64) * 16,
                    vbase + (size_t)row * M_ + k0s + gsw * 8);
        }
    };

    ushort_t* Pw = Ps[wv];
    const int psw = lo & 7;

    stage(0, 0);
    for (int kt = 0; kt <= qt; ++kt) {
        const int bb = kt & 1;
        const int k0 = kt * 64;
        __syncthreads();
        if (kt < qt) stage(bb ^ 1, kt + 1);

        const int diff = q0 + wv * 16 - k0;   // >= 0 always (kt <= qt)
        const int cmax = diff >= 48 ? 3 : (diff >> 4);

        f32x4 sacc[4];
#pragma unroll
        for (int kt16 = 0; kt16 < 4; ++kt16) {
            if (kt16 <= cmax) {
                int row = kt16 * 16 + lo, sw = row & 7;
                short8 kf0 = *(const short8*)(&Ks[bb][0] + row * 64 + (hi ^ sw) * 8);
                short8 kf1 = *(const short8*)(&Ks[bb][0] + row * 64 + ((4 + hi) ^ sw) * 8);
                f32x4 z = (f32x4){0.f, 0.f, 0.f, 0.f};
                z = __builtin_amdgcn_mfma_f32_16x16x32_bf16(kf0, qf[0], z, 0, 0, 0);
                z = __builtin_amdgcn_mfma_f32_16x16x32_bf16(kf1, qf[1], z, 0, 0, 0);
#pragma unroll
                for (int r = 0; r < 4; ++r) sacc[kt16][r] = z[r] * SC;
            } else {
                sacc[kt16] = NEG4;
            }
        }
        if (diff < 64) {  // diagonal subtile: element mask key > qrow
            const int qrow = diff + lo;
#pragma unroll
            for (int r = 0; r < 4; ++r) {
                int key = cmax * 16 + 4 * hi + r;
                if (key > qrow) sacc[cmax][r] = -1e30f;
            }
        }

        // ---- online softmax (rows = lo), packed P spill ----
        float mx = -1e30f;
#pragma unroll
        for (int kt16 = 0; kt16 < 4; ++kt16)
#pragma unroll
            for (int r = 0; r < 4; ++r) mx = fmaxf(mx, sacc[kt16][r]);
        mx = fmaxf(mx, __shfl_xor(mx, 16, 64));
        mx = fmaxf(mx, __shfl_xor(mx, 32, 64));
        float mnew = fmaxf(m_r, mx);
        float alpha = fexp2(m_r - mnew);
        m_r = mnew;
        float rs = 0.f;
#pragma unroll
        for (int kt16 = 0; kt16 < 4; ++kt16) {
            float p0 = fexp2(sacc[kt16][0] - mnew);
            float p1 = fexp2(sacc[kt16][1] - mnew);
            float p2 = fexp2(sacc[kt16][2] - mnew);
            float p3 = fexp2(sacc[kt16][3] - mnew);
            rs += p0 + p1 + p2 + p3;
            ushort4 pk;
            pk.x = f2bf(p0); pk.y = f2bf(p1); pk.z = f2bf(p2); pk.w = f2bf(p3);
            // key s = kt16*16 + 4*hi + r -> chunk 2*kt16 + (hi>>1), offset 4*(hi&1)
            *(ushort4*)(Pw + lo * 64 + (((2 * kt16 + (hi >> 1)) ^ psw) << 3) + 4 * (hi & 1)) = pk;
        }
        rs += __shfl_xor(rs, 16, 64);
        rs += __shfl_xor(rs, 32, 64);
        l_r = l_r * alpha + rs;
#pragma unroll
        for (int r = 0; r < 4; ++r) {
            float ab = __shfl(alpha, 4 * hi + r, 64);
#pragma unroll
            for (int dt = 0; dt < 4; ++dt) o_acc[dt][r] *= ab;
        }

        // ---- read P fragments back (same-wave LDS, in-order) ----
        short8 pf0 = *(const short8*)(Pw + lo * 64 + ((hi ^ psw) << 3));
        short8 pf1 = *(const short8*)(Pw + lo * 64 + (((4 + hi) ^ psw) << 3));

        // ---- PV ----
#pragma unroll
        for (int dt = 0; dt < 4; ++dt) {
            int row = dt * 16 + lo, sw = row & 7;
            short8 vf0 = *(const short8*)(&VTs[bb][0] + row * 64 + (hi ^ sw) * 8);
            short8 vf1 = *(const short8*)(&VTs[bb][0] + row * 64 + ((4 + hi) ^ sw) * 8);
            o_acc[dt] = __builtin_amdgcn_mfma_f32_16x16x32_bf16(pf0, vf0, o_acc[dt], 0, 0, 0);
            o_acc[dt] = __builtin_amdgcn_mfma_f32_16x16x32_bf16(pf1, vf1, o_acc[dt], 0, 0, 0);
        }
    }

#pragma unroll
    for (int r = 0; r < 4; ++r) {
        float lb = __shfl(l_r, 4 * hi + r, 64);
        float inv = 1.0f / lb;
        size_t row = rowbase + (size_t)(q0 + wv * 16 + 4 * hi + r) * 1024 + headoff;
#pragma unroll
        for (int dt = 0; dt < 4; ++dt)
            ctx[row + dt * 16 + lo] = f2bf(o_acc[dt][r] * inv);
    }
}

// ---------------------------------------------------------------------------
extern "C" void kernel_launch(void* const* d_in, const int* in_sizes, int n_in,
                              void* d_out, int out_size, void* d_ws, size_t ws_size,
                              hipStream_t stream) {
    (void)in_sizes; (void)n_in; (void)out_size; (void)ws_size;
    const float* x    = (const float*)d_in[0];
    const float* Wq   = (const float*)d_in[1];
    const float* bq   = (const float*)d_in[2];
    const float* Wk   = (const float*)d_in[3];
    const float* bk   = (const float*)d_in[4];
    const float* Wv   = (const float*)d_in[5];
    const float* bv   = (const float*)d_in[6];
    const float* Wo   = (const float*)d_in[7];
    const float* bo   = (const float*)d_in[8];
    const float* W1   = (const float*)d_in[9];
    const float* b1   = (const float*)d_in[10];
    const float* W2   = (const float*)d_in[11];
    const float* b2   = (const float*)d_in[12];
    const float* ln1s = (const float*)d_in[13];
    const float* ln1b = (const float*)d_in[14];
    const float* ln2s = (const float*)d_in[15];
    const float* ln2b = (const float*)d_in[16];

    char* ws = (char*)d_ws;
    const size_t MB = 1024 * 1024;
    ushort_t* wqkv = (ushort_t*)(ws + 0 * MB);   // wtq|wtk|wtv contiguous [3072][1024]
    ushort_t* wtq  = (ushort_t*)(ws + 0 * MB);
    ushort_t* wtk  = (ushort_t*)(ws + 2 * MB);
    ushort_t* wtv  = (ushort_t*)(ws + 4 * MB);
    ushort_t* wto  = (ushort_t*)(ws + 6 * MB);
    ushort_t* wt1  = (ushort_t*)(ws + 8 * MB);   // 8MB (4096x1024)
    ushort_t* wt2  = (ushort_t*)(ws + 16 * MB);  // 8MB (1024x4096)
    ushort_t* hbuf = (ushort_t*)(ws + 24 * MB);  // 8MB
    ushort_t* qb_  = (ushort_t*)(ws + 32 * MB);  // 8MB
    ushort_t* kb_  = (ushort_t*)(ws + 40 * MB);  // 8MB
    ushort_t* ctx  = (ushort_t*)(ws + 56 * MB);  // 8MB
    ushort_t* hid  = (ushort_t*)(ws + 32 * MB);  // 32MB, reuses q/k/ctx post-attn
    float*    x1   = (float*)(ws + 64 * MB);     // 16MB fp32 (written after attn)
    ushort_t* vtb  = (ushort_t*)(ws + 64 * MB);  // 8MB [1024][4096], dead after attn

    transpose_all_k<<<12288, dim3(32, 8), 0, stream>>>(Wq, Wk, Wv, Wo, W1, W2,
                                                       wtq, wtk, wtv, wto, wt1, wt2);

    ln_kernel<<<4096, 256, 0, stream>>>(x, ln1s, ln1b, hbuf);

    // fused QKV (256^2 double-barrier 8-phase); seg2 writes v^T into vtb
    gemm256<3><<<dim3(12, 16), 512, 0, stream>>>(hbuf, wqkv, bq, bk, bv,
                                                 qb_, kb_, vtb, 4096, 3072, 1024);

    attn_kernel<<<1024, 256, 0, stream>>>(qb_, kb_, vtb, ctx);

    // Wo projection (m97 2-phase, known-good): x1 = x + bo + ctx @ Wo^T
    gemm_bt<2, 1><<<dim3(8, 64), 256, 0, stream>>>(ctx, wto, bo, x,
                                                   x1, 4096, 1024, 1024);

    ln_kernel<<<4096, 256, 0, stream>>>(x1, ln2s, ln2b, hbuf);

    // FF1 (256^2 double-barrier 8-phase, gelu epilogue)
    gemm256<2><<<dim3(16, 16), 512, 0, stream>>>(hbuf, wt1, b1, nullptr, nullptr,
                                                 hid, nullptr, nullptr, 4096, 4096, 1024);

    // FF2 (m97 2-phase, known-good): d_out = x1 + b2 + hid @ W2^T
    gemm_bt<2, 1><<<dim3(8, 64), 256, 0, stream>>>(hid, wt2, b2, x1,
                                                   (float*)d_out, 4096, 1024, 4096);
}

// Round 5
// 375.778 us; speedup vs baseline: 1.1676x; 1.0636x over previous
//
#include <hip/hip_runtime.h>
#include <hip/hip_bf16.h>
#include <stdint.h>

#define B_ 2
#define T_ 2048
#define C_ 1024
#define H_ 16
#define D_ 64
#define F_ 4096
#define M_ (B_*T_)

typedef unsigned short ushort_t;
typedef __attribute__((ext_vector_type(8))) short short8;
typedef __attribute__((ext_vector_type(4))) float f32x4;

__device__ __forceinline__ float bf2f(ushort_t u) {
    union { unsigned u; float f; } c; c.u = ((unsigned)u) << 16; return c.f;
}
__device__ __forceinline__ ushort_t f2bf(float f) {
    union { float f; unsigned u; } c; c.f = f;
    unsigned u = c.u;
    unsigned r = (u + 0x7FFFu + ((u >> 16) & 1u)) >> 16;
    return (ushort_t)r;
}

__device__ __forceinline__ float fexp2(float x) { return __builtin_amdgcn_exp2f(x); }

// async global->LDS, 16B per lane. LDS dest = wave-uniform base + lane*16.
__device__ __forceinline__ void async16(void* lds, const void* g) {
    __builtin_amdgcn_global_load_lds(
        (const __attribute__((address_space(1))) unsigned int*)(uintptr_t)g,
        (__attribute__((address_space(3))) unsigned int*)(uintptr_t)lds,
        16, 0, 0);
}

// ---------------------------------------------------------------------------
// Batched transpose+cast of all 6 weights: out_bf16[c][r] = in_f32[r][c]
// ---------------------------------------------------------------------------
__global__ __launch_bounds__(256) void transpose_all_k(
    const float* __restrict__ Wq, const float* __restrict__ Wk,
    const float* __restrict__ Wv, const float* __restrict__ Wo,
    const float* __restrict__ W1, const float* __restrict__ W2,
    ushort_t* __restrict__ oq, ushort_t* __restrict__ ok,
    ushort_t* __restrict__ ov, ushort_t* __restrict__ oo,
    ushort_t* __restrict__ o1, ushort_t* __restrict__ o2) {
    __shared__ ushort_t tile[32][33];
    int id = blockIdx.x;
    const float* in; ushort_t* out; int R, Cc, bx, by;
    if (id < 4096) {
        int w = id >> 10, loc = id & 1023;
        in  = w == 0 ? Wq : w == 1 ? Wk : w == 2 ? Wv : Wo;
        out = w == 0 ? oq : w == 1 ? ok : w == 2 ? ov : oo;
        R = 1024; Cc = 1024; bx = loc & 31; by = loc >> 5;
    } else if (id < 8192) {
        int loc = id - 4096; in = W1; out = o1; R = 1024; Cc = 4096;
        bx = loc & 127; by = loc >> 7;
    } else {
        int loc = id - 8192; in = W2; out = o2; R = 4096; Cc = 1024;
        bx = loc & 31; by = loc >> 5;
    }
    int tx = threadIdx.x, ty = threadIdx.y;
    int x = bx * 32 + tx;
    int y0 = by * 32;
#pragma unroll
    for (int i = 0; i < 32; i += 8)
        tile[ty + i][tx] = f2bf(in[(size_t)(y0 + ty + i) * Cc + x]);
    __syncthreads();
    int x2 = y0 + tx;
    int y2 = bx * 32;
#pragma unroll
    for (int i = 0; i < 32; i += 8)
        out[(size_t)(y2 + ty + i) * R + x2] = tile[tx][ty + i];
}

// ---------------------------------------------------------------------------
// LayerNorm: fp32 input row of 1024, fp32 scale/shift, bf16 output.
// ---------------------------------------------------------------------------
__global__ __launch_bounds__(256) void ln_kernel(const float* __restrict__ xin,
                                                 const float* __restrict__ scale_p,
                                                 const float* __restrict__ shift_p,
                                                 ushort_t* __restrict__ out) {
    int row = blockIdx.x, t = threadIdx.x;
    int wv = t >> 6, lane = t & 63;
    const float* xr = xin + (size_t)row * 1024 + t * 4;
    float4 v = *(const float4*)xr;
    float f[4] = {v.x, v.y, v.z, v.w};
    float s = f[0] + f[1] + f[2] + f[3];
    float q = f[0]*f[0] + f[1]*f[1] + f[2]*f[2] + f[3]*f[3];
#pragma unroll
    for (int off = 1; off < 64; off <<= 1) {
        s += __shfl_xor(s, off, 64);
        q += __shfl_xor(q, off, 64);
    }
    __shared__ float sh_s[4], sh_q[4];
    if (lane == 0) { sh_s[wv] = s; sh_q[wv] = q; }
    __syncthreads();
    float S = sh_s[0] + sh_s[1] + sh_s[2] + sh_s[3];
    float Q = sh_q[0] + sh_q[1] + sh_q[2] + sh_q[3];
    float mean = S * (1.0f / 1024.0f);
    float var = Q * (1.0f / 1024.0f) - mean * mean;
    float rstd = rsqrtf(var + 1e-5f);
    float4 scv = *(const float4*)(scale_p + t * 4);
    float4 shv = *(const float4*)(shift_p + t * 4);
    ushort4 o;
    o.x = f2bf((f[0] - mean) * rstd * scv.x + shv.x);
    o.y = f2bf((f[1] - mean) * rstd * scv.y + shv.y);
    o.z = f2bf((f[2] - mean) * rstd * scv.z + shv.z);
    o.w = f2bf((f[3] - mean) * rstd * scv.w + shv.w);
    *(ushort4*)(out + (size_t)row * 1024 + t * 4) = o;
}

// ---------------------------------------------------------------------------
// GEMM, double-buffered m97 structure (T3 minimum-2-phase recipe):
//   prologue: STAGE(buf0, k=0); __syncthreads;
//   iter k:   STAGE(buf^1, k+1); ds_read+MFMA on buf; __syncthreads; swap.
// One barrier per K-iter; the vmcnt/lgkm drain lands AFTER the compute so
// staging latency hides under MFMA + other blocks (3-5 blocks/CU by LDS).
// XCD-chunked block swizzle: each XCD gets contiguous row-panels -> the
// col-blocks sharing an A-panel hit the same L2 (requires nwg % 8 == 0).
// C[M,N] = A[M,K](bf16) @ Bt[N,K](bf16)^T + bias; tile (32*MT) x 128, BK=32.
// EPI: 1 = +f32 residual, f32 out; 2 = gelu, bf16 out
//      3 = QKV split: seg0/1 -> q,k row-major bf16 [.][1024]; seg2 -> v^T
// ---------------------------------------------------------------------------
template <int MT, int EPI>
__global__ __launch_bounds__(256) void gemm_bt(const ushort_t* __restrict__ A,
                                               const ushort_t* __restrict__ Bt,
                                               const float* __restrict__ b0,
                                               const float* __restrict__ b1,
                                               const float* __restrict__ b2,
                                               const float* __restrict__ res,
                                               void* __restrict__ out0,
                                               void* __restrict__ out1,
                                               void* __restrict__ out2,
                                               int M, int N, int K) {
    __shared__ ushort_t As[2][32 * MT * 32];
    __shared__ ushort_t Bs[2][128 * 32];
    const int t = threadIdx.x;
    const int wv = t >> 6, lane = t & 63, lo = lane & 15, hi = lane >> 4;
    const int wr = wv >> 1, wc = wv & 1;

    // XCD-chunked swizzle (dispatch id d -> XCD d%8; give each XCD a
    // contiguous chunk of the x-major tile order = complete row-panels)
    const int nwg = gridDim.x * gridDim.y;
    const int id = blockIdx.y * gridDim.x + blockIdx.x;
    const int swz = (id & 7) * (nwg >> 3) + (id >> 3);
    const int nb = swz % gridDim.x, mb = swz / gridDim.x;

    f32x4 acc[MT][4];
#pragma unroll
    for (int i = 0; i < MT; ++i)
#pragma unroll
        for (int j = 0; j < 4; ++j) acc[i][j] = (f32x4){0.f, 0.f, 0.f, 0.f};

    auto STAGE = [&](int bf, int k0) {
#pragma unroll
        for (int i = 0; i < MT / 2; ++i) {
            int c = i * 256 + t;
            int row = c >> 2, kc = c & 3;
            async16((char*)&As[bf][0] + (size_t)(i * 256 + wv * 64) * 16,
                    A + (size_t)(mb * 32 * MT + row) * K + k0 + kc * 8);
        }
#pragma unroll
        for (int i = 0; i < 2; ++i) {
            int c = i * 256 + t;
            int row = c >> 2, kc = c & 3;
            async16((char*)&Bs[bf][0] + (size_t)(i * 256 + wv * 64) * 16,
                    Bt + (size_t)(nb * 128 + row) * K + k0 + kc * 8);
        }
    };

    STAGE(0, 0);
    __syncthreads();

    const int NI = K >> 5;
    int bf = 0;
    for (int ki = 0; ki < NI; ++ki) {
        if (ki + 1 < NI) STAGE(bf ^ 1, (ki + 1) << 5);

        short8 af[MT], bfr[4];
#pragma unroll
        for (int mi = 0; mi < MT; ++mi)
            af[mi] = *(const short8*)(&As[bf][0] + (wr * 16 * MT + mi * 16 + lo) * 32 + hi * 8);
#pragma unroll
        for (int ni = 0; ni < 4; ++ni)
            bfr[ni] = *(const short8*)(&Bs[bf][0] + (wc * 64 + ni * 16 + lo) * 32 + hi * 8);
#pragma unroll
        for (int mi = 0; mi < MT; ++mi)
#pragma unroll
            for (int ni = 0; ni < 4; ++ni)
                acc[mi][ni] = __builtin_amdgcn_mfma_f32_16x16x32_bf16(
                    af[mi], bfr[ni], acc[mi][ni], 0, 0, 0);

        __syncthreads();   // drains vmcnt(0)+lgkm(0) AFTER compute; one barrier/iter
        bf ^= 1;
    }

#pragma unroll
    for (int ni = 0; ni < 4; ++ni) {
        int n = nb * 128 + wc * 64 + ni * 16 + lo;
        float bn;
        ushort_t* obf = nullptr;
        int coln = n, seg = 0;
        if (EPI == 3) {
            seg = n >> 10; coln = n & 1023;
            bn = (seg == 0 ? b0 : seg == 1 ? b1 : b2)[coln];
            obf = (ushort_t*)(seg == 0 ? out0 : out1);
        } else {
            bn = b0[n];
        }
#pragma unroll
        for (int mi = 0; mi < MT; ++mi) {
            if (EPI == 3 && seg == 2) {
                int m0 = mb * 32 * MT + wr * 16 * MT + mi * 16 + 4 * hi;
                ushort4 pk;
                pk.x = f2bf(acc[mi][ni][0] + bn);
                pk.y = f2bf(acc[mi][ni][1] + bn);
                pk.z = f2bf(acc[mi][ni][2] + bn);
                pk.w = f2bf(acc[mi][ni][3] + bn);
                *(ushort4*)((ushort_t*)out2 + (size_t)coln * M + m0) = pk;
            } else {
#pragma unroll
                for (int r = 0; r < 4; ++r) {
                    int m = mb * 32 * MT + wr * 16 * MT + mi * 16 + 4 * hi + r;
                    float v = acc[mi][ni][r] + bn;
                    if (EPI == 1) {
                        size_t idx = (size_t)m * N + n;
                        ((float*)out0)[idx] = v + res[idx];
                    } else if (EPI == 2) {
                        v = 0.5f * v * (1.0f + erff(v * 0.70710678118654752f));
                        ((ushort_t*)out0)[(size_t)m * N + n] = f2bf(v);
                    } else {
                        obf[(size_t)m * 1024 + coln] = f2bf(v);
                    }
                }
            }
        }
    }
}

// ---------------------------------------------------------------------------
// Causal flash attention: 64-row q-tiles, grid 1024 (32 qt x 32 bh),
// longest strips dispatched first; 4 blocks/CU (LDS = 40960).
// ---------------------------------------------------------------------------
__global__ __launch_bounds__(256) void attn_kernel(const ushort_t* __restrict__ q,
                                                   const ushort_t* __restrict__ k,
                                                   const ushort_t* __restrict__ vt,
                                                   ushort_t* __restrict__ ctx) {
    __shared__ ushort_t Ks[2][64 * 64];   // [buf][key][d], col-chunk swizzled
    __shared__ ushort_t VTs[2][64 * 64];  // [buf][d][key], col-chunk swizzled
    __shared__ ushort_t Ps[4][16 * 64];   // [wave][qrow][key], XOR-swizzled chunks

    const int t = threadIdx.x;
    const int wv = t >> 6, lane = t & 63, lo = lane & 15, hi = lane >> 4;
    const int id = blockIdx.x;             // 1024
    const int qt = 31 - (id >> 5);         // longest-first
    const int bh = id & 31, b = bh >> 4, h = bh & 15;
    const int q0 = qt * 64;
    const size_t headoff = (size_t)h * 64;
    const size_t rowbase = (size_t)b * T_ * 1024;
    const ushort_t* vbase = vt + headoff * (size_t)M_ + (size_t)b * T_;

    short8 qf[2];
    {
        const ushort_t* qp = q + rowbase + (size_t)(q0 + wv * 16 + lo) * 1024 + headoff;
        qf[0] = *(const short8*)(qp + hi * 8);
        qf[1] = *(const short8*)(qp + 32 + hi * 8);
    }

    float m_r = -1e30f, l_r = 0.f;
    f32x4 o_acc[4];
#pragma unroll
    for (int dt = 0; dt < 4; ++dt) o_acc[dt] = (f32x4){0.f, 0.f, 0.f, 0.f};

    const float SC = 0.18033688011112042f;  // 0.125 * log2(e)
    const f32x4 NEG4 = (f32x4){-1e30f, -1e30f, -1e30f, -1e30f};

    auto stage = [&](int bb, int kt) {
        const int k0s = kt * 64;
#pragma unroll
        for (int i = 0; i < 2; ++i) {
            int c = i * 256 + t;
            int row = c >> 3, c8 = c & 7;
            int gsw = c8 ^ (row & 7);
            async16((char*)&Ks[bb][0] + (size_t)(i * 256 + wv * 64) * 16,
                    k + rowbase + (size_t)(k0s + row) * 1024 + headoff + gsw * 8);
            async16((char*)&VTs[bb][0] + (size_t)(i * 256 + wv * 64) * 16,
                    vbase + (size_t)row * M_ + k0s + gsw * 8);
        }
    };

    ushort_t* Pw = Ps[wv];
    const int psw = lo & 7;

    stage(0, 0);
    for (int kt = 0; kt <= qt; ++kt) {
        const int bb = kt & 1;
        const int k0 = kt * 64;
        __syncthreads();
        if (kt < qt) stage(bb ^ 1, kt + 1);

        const int diff = q0 + wv * 16 - k0;   // >= 0 always (kt <= qt)
        const int cmax = diff >= 48 ? 3 : (diff >> 4);

        f32x4 sacc[4];
#pragma unroll
        for (int kt16 = 0; kt16 < 4; ++kt16) {
            if (kt16 <= cmax) {
                int row = kt16 * 16 + lo, sw = row & 7;
                short8 kf0 = *(const short8*)(&Ks[bb][0] + row * 64 + (hi ^ sw) * 8);
                short8 kf1 = *(const short8*)(&Ks[bb][0] + row * 64 + ((4 + hi) ^ sw) * 8);
                f32x4 z = (f32x4){0.f, 0.f, 0.f, 0.f};
                z = __builtin_amdgcn_mfma_f32_16x16x32_bf16(kf0, qf[0], z, 0, 0, 0);
                z = __builtin_amdgcn_mfma_f32_16x16x32_bf16(kf1, qf[1], z, 0, 0, 0);
#pragma unroll
                for (int r = 0; r < 4; ++r) sacc[kt16][r] = z[r] * SC;
            } else {
                sacc[kt16] = NEG4;
            }
        }
        if (diff < 64) {  // diagonal subtile: element mask key > qrow
            const int qrow = diff + lo;
#pragma unroll
            for (int r = 0; r < 4; ++r) {
                int key = cmax * 16 + 4 * hi + r;
                if (key > qrow) sacc[cmax][r] = -1e30f;
            }
        }

        // ---- online softmax (rows = lo), packed P spill ----
        float mx = -1e30f;
#pragma unroll
        for (int kt16 = 0; kt16 < 4; ++kt16)
#pragma unroll
            for (int r = 0; r < 4; ++r) mx = fmaxf(mx, sacc[kt16][r]);
        mx = fmaxf(mx, __shfl_xor(mx, 16, 64));
        mx = fmaxf(mx, __shfl_xor(mx, 32, 64));
        float mnew = fmaxf(m_r, mx);
        float alpha = fexp2(m_r - mnew);
        m_r = mnew;
        float rs = 0.f;
#pragma unroll
        for (int kt16 = 0; kt16 < 4; ++kt16) {
            float p0 = fexp2(sacc[kt16][0] - mnew);
            float p1 = fexp2(sacc[kt16][1] - mnew);
            float p2 = fexp2(sacc[kt16][2] - mnew);
            float p3 = fexp2(sacc[kt16][3] - mnew);
            rs += p0 + p1 + p2 + p3;
            ushort4 pk;
            pk.x = f2bf(p0); pk.y = f2bf(p1); pk.z = f2bf(p2); pk.w = f2bf(p3);
            // key s = kt16*16 + 4*hi + r -> chunk 2*kt16 + (hi>>1), offset 4*(hi&1)
            *(ushort4*)(Pw + lo * 64 + (((2 * kt16 + (hi >> 1)) ^ psw) << 3) + 4 * (hi & 1)) = pk;
        }
        rs += __shfl_xor(rs, 16, 64);
        rs += __shfl_xor(rs, 32, 64);
        l_r = l_r * alpha + rs;
#pragma unroll
        for (int r = 0; r < 4; ++r) {
            float ab = __shfl(alpha, 4 * hi + r, 64);
#pragma unroll
            for (int dt = 0; dt < 4; ++dt) o_acc[dt][r] *= ab;
        }

        // ---- read P fragments back (same-wave LDS, in-order) ----
        short8 pf0 = *(const short8*)(Pw + lo * 64 + ((hi ^ psw) << 3));
        short8 pf1 = *(const short8*)(Pw + lo * 64 + (((4 + hi) ^ psw) << 3));

        // ---- PV ----
#pragma unroll
        for (int dt = 0; dt < 4; ++dt) {
            int row = dt * 16 + lo, sw = row & 7;
            short8 vf0 = *(const short8*)(&VTs[bb][0] + row * 64 + (hi ^ sw) * 8);
            short8 vf1 = *(const short8*)(&VTs[bb][0] + row * 64 + ((4 + hi) ^ sw) * 8);
            o_acc[dt] = __builtin_amdgcn_mfma_f32_16x16x32_bf16(pf0, vf0, o_acc[dt], 0, 0, 0);
            o_acc[dt] = __builtin_amdgcn_mfma_f32_16x16x32_bf16(pf1, vf1, o_acc[dt], 0, 0, 0);
        }
    }

#pragma unroll
    for (int r = 0; r < 4; ++r) {
        float lb = __shfl(l_r, 4 * hi + r, 64);
        float inv = 1.0f / lb;
        size_t row = rowbase + (size_t)(q0 + wv * 16 + 4 * hi + r) * 1024 + headoff;
#pragma unroll
        for (int dt = 0; dt < 4; ++dt)
            ctx[row + dt * 16 + lo] = f2bf(o_acc[dt][r] * inv);
    }
}

// ---------------------------------------------------------------------------
extern "C" void kernel_launch(void* const* d_in, const int* in_sizes, int n_in,
                              void* d_out, int out_size, void* d_ws, size_t ws_size,
                              hipStream_t stream) {
    (void)in_sizes; (void)n_in; (void)out_size; (void)ws_size;
    const float* x    = (const float*)d_in[0];
    const float* Wq   = (const float*)d_in[1];
    const float* bq   = (const float*)d_in[2];
    const float* Wk   = (const float*)d_in[3];
    const float* bk   = (const float*)d_in[4];
    const float* Wv   = (const float*)d_in[5];
    const float* bv   = (const float*)d_in[6];
    const float* Wo   = (const float*)d_in[7];
    const float* bo   = (const float*)d_in[8];
    const float* W1   = (const float*)d_in[9];
    const float* b1   = (const float*)d_in[10];
    const float* W2   = (const float*)d_in[11];
    const float* b2   = (const float*)d_in[12];
    const float* ln1s = (const float*)d_in[13];
    const float* ln1b = (const float*)d_in[14];
    const float* ln2s = (const float*)d_in[15];
    const float* ln2b = (const float*)d_in[16];

    char* ws = (char*)d_ws;
    const size_t MB = 1024 * 1024;
    ushort_t* wqkv = (ushort_t*)(ws + 0 * MB);   // wtq|wtk|wtv contiguous [3072][1024]
    ushort_t* wtq  = (ushort_t*)(ws + 0 * MB);
    ushort_t* wtk  = (ushort_t*)(ws + 2 * MB);
    ushort_t* wtv  = (ushort_t*)(ws + 4 * MB);
    ushort_t* wto  = (ushort_t*)(ws + 6 * MB);
    ushort_t* wt1  = (ushort_t*)(ws + 8 * MB);   // 8MB (4096x1024)
    ushort_t* wt2  = (ushort_t*)(ws + 16 * MB);  // 8MB (1024x4096)
    ushort_t* hbuf = (ushort_t*)(ws + 24 * MB);  // 8MB
    ushort_t* qb_  = (ushort_t*)(ws + 32 * MB);  // 8MB
    ushort_t* kb_  = (ushort_t*)(ws + 40 * MB);  // 8MB
    ushort_t* ctx  = (ushort_t*)(ws + 56 * MB);  // 8MB
    ushort_t* hid  = (ushort_t*)(ws + 32 * MB);  // 32MB, reuses q/k/ctx post-attn
    float*    x1   = (float*)(ws + 64 * MB);     // 16MB fp32 (written after attn)
    ushort_t* vtb  = (ushort_t*)(ws + 64 * MB);  // 8MB [1024][4096], dead after attn

    transpose_all_k<<<12288, dim3(32, 8), 0, stream>>>(Wq, Wk, Wv, Wo, W1, W2,
                                                       wtq, wtk, wtv, wto, wt1, wt2);

    ln_kernel<<<4096, 256, 0, stream>>>(x, ln1s, ln1b, hbuf);

    // fused QKV (dbuf m97); seg2 writes v^T directly into vtb [1024][4096]
    gemm_bt<4, 3><<<dim3(24, 32), 256, 0, stream>>>(hbuf, wqkv, bq, bk, bv, nullptr,
                                                    qb_, kb_, vtb, 4096, 3072, 1024);

    attn_kernel<<<1024, 256, 0, stream>>>(qb_, kb_, vtb, ctx);

    // Wo projection: x1 = x + bo + ctx @ Wo^T
    gemm_bt<2, 1><<<dim3(8, 64), 256, 0, stream>>>(ctx, wto, bo, nullptr, nullptr, x,
                                                   x1, nullptr, nullptr, 4096, 1024, 1024);

    ln_kernel<<<4096, 256, 0, stream>>>(x1, ln2s, ln2b, hbuf);

    // FF1 (dbuf m97, gelu epilogue)
    gemm_bt<4, 2><<<dim3(32, 32), 256, 0, stream>>>(hbuf, wt1, b1, nullptr, nullptr, nullptr,
                                                    hid, nullptr, nullptr, 4096, 4096, 1024);

    // FF2: d_out = x1 + b2 + hid @ W2^T
    gemm_bt<2, 1><<<dim3(8, 64), 256, 0, stream>>>(hid, wt2, b2, nullptr, nullptr, x1,
                                                   (float*)d_out, nullptr, nullptr, 4096, 1024, 4096);
}

// Round 6
// 363.676 us; speedup vs baseline: 1.2065x; 1.0333x over previous
//
#include <hip/hip_runtime.h>
#include <hip/hip_bf16.h>
#include <stdint.h>

#define B_ 2
#define T_ 2048
#define C_ 1024
#define H_ 16
#define D_ 64
#define F_ 4096
#define M_ (B_*T_)

typedef unsigned short ushort_t;
typedef __attribute__((ext_vector_type(8))) short short8;
typedef __attribute__((ext_vector_type(4))) float f32x4;

__device__ __forceinline__ float bf2f(ushort_t u) {
    union { unsigned u; float f; } c; c.u = ((unsigned)u) << 16; return c.f;
}
__device__ __forceinline__ ushort_t f2bf(float f) {
    union { float f; unsigned u; } c; c.f = f;
    unsigned u = c.u;
    unsigned r = (u + 0x7FFFu + ((u >> 16) & 1u)) >> 16;
    return (ushort_t)r;
}

__device__ __forceinline__ float fexp2(float x) { return __builtin_amdgcn_exp2f(x); }

// async global->LDS, 16B per lane. LDS dest = wave-uniform base + lane*16.
__device__ __forceinline__ void async16(void* lds, const void* g) {
    __builtin_amdgcn_global_load_lds(
        (const __attribute__((address_space(1))) unsigned int*)(uintptr_t)g,
        (__attribute__((address_space(3))) unsigned int*)(uintptr_t)lds,
        16, 0, 0);
}

// ---------------------------------------------------------------------------
// Batched transpose+cast of all 6 weights: out_bf16[c][r] = in_f32[r][c]
// ---------------------------------------------------------------------------
__global__ __launch_bounds__(256) void transpose_all_k(
    const float* __restrict__ Wq, const float* __restrict__ Wk,
    const float* __restrict__ Wv, const float* __restrict__ Wo,
    const float* __restrict__ W1, const float* __restrict__ W2,
    ushort_t* __restrict__ oq, ushort_t* __restrict__ ok,
    ushort_t* __restrict__ ov, ushort_t* __restrict__ oo,
    ushort_t* __restrict__ o1, ushort_t* __restrict__ o2) {
    __shared__ ushort_t tile[32][33];
    int id = blockIdx.x;
    const float* in; ushort_t* out; int R, Cc, bx, by;
    if (id < 4096) {
        int w = id >> 10, loc = id & 1023;
        in  = w == 0 ? Wq : w == 1 ? Wk : w == 2 ? Wv : Wo;
        out = w == 0 ? oq : w == 1 ? ok : w == 2 ? ov : oo;
        R = 1024; Cc = 1024; bx = loc & 31; by = loc >> 5;
    } else if (id < 8192) {
        int loc = id - 4096; in = W1; out = o1; R = 1024; Cc = 4096;
        bx = loc & 127; by = loc >> 7;
    } else {
        int loc = id - 8192; in = W2; out = o2; R = 4096; Cc = 1024;
        bx = loc & 31; by = loc >> 5;
    }
    int tx = threadIdx.x, ty = threadIdx.y;
    int x = bx * 32 + tx;
    int y0 = by * 32;
#pragma unroll
    for (int i = 0; i < 32; i += 8)
        tile[ty + i][tx] = f2bf(in[(size_t)(y0 + ty + i) * Cc + x]);
    __syncthreads();
    int x2 = y0 + tx;
    int y2 = bx * 32;
#pragma unroll
    for (int i = 0; i < 32; i += 8)
        out[(size_t)(y2 + ty + i) * R + x2] = tile[tx][ty + i];
}

// ---------------------------------------------------------------------------
// LayerNorm: fp32 input row of 1024, fp32 scale/shift, bf16 output.
// ---------------------------------------------------------------------------
__global__ __launch_bounds__(256) void ln_kernel(const float* __restrict__ xin,
                                                 const float* __restrict__ scale_p,
                                                 const float* __restrict__ shift_p,
                                                 ushort_t* __restrict__ out) {
    int row = blockIdx.x, t = threadIdx.x;
    int wv = t >> 6, lane = t & 63;
    const float* xr = xin + (size_t)row * 1024 + t * 4;
    float4 v = *(const float4*)xr;
    float f[4] = {v.x, v.y, v.z, v.w};
    float s = f[0] + f[1] + f[2] + f[3];
    float q = f[0]*f[0] + f[1]*f[1] + f[2]*f[2] + f[3]*f[3];
#pragma unroll
    for (int off = 1; off < 64; off <<= 1) {
        s += __shfl_xor(s, off, 64);
        q += __shfl_xor(q, off, 64);
    }
    __shared__ float sh_s[4], sh_q[4];
    if (lane == 0) { sh_s[wv] = s; sh_q[wv] = q; }
    __syncthreads();
    float S = sh_s[0] + sh_s[1] + sh_s[2] + sh_s[3];
    float Q = sh_q[0] + sh_q[1] + sh_q[2] + sh_q[3];
    float mean = S * (1.0f / 1024.0f);
    float var = Q * (1.0f / 1024.0f) - mean * mean;
    float rstd = rsqrtf(var + 1e-5f);
    float4 scv = *(const float4*)(scale_p + t * 4);
    float4 shv = *(const float4*)(shift_p + t * 4);
    ushort4 o;
    o.x = f2bf((f[0] - mean) * rstd * scv.x + shv.x);
    o.y = f2bf((f[1] - mean) * rstd * scv.y + shv.y);
    o.z = f2bf((f[2] - mean) * rstd * scv.z + shv.z);
    o.w = f2bf((f[3] - mean) * rstd * scv.w + shv.w);
    *(ushort4*)(out + (size_t)row * 1024 + t * 4) = o;
}

// ---------------------------------------------------------------------------
// GEMM, double-buffered m97 structure + bank-conflict-free chunk swizzle:
//   prologue: STAGE(buf0, k=0); __syncthreads;
//   iter k:   STAGE(buf^1, k+1); ds_read+MFMA on buf; __syncthreads; swap.
// LDS rows are 32 elems (64B). Both-sides XOR swizzle (rule #21):
//   staging source chunk kc -> kc ^ ((row>>1)&3) (LDS dest stays linear,
//   required by global_load_lds); fragment read chunk hi -> hi ^ ((lo>>1)&3).
// Quarter-wave bank pattern: 16*(row&1) + 4*(hi^((row>>1)&3)) covers all 8
// combos twice -> 2 lanes/bank = free (m136).  Was 8-way (4.2M conflicts).
// XCD-chunked block swizzle (requires nwg % 8 == 0).
// C[M,N] = A[M,K](bf16) @ Bt[N,K](bf16)^T + bias; tile (32*MT) x 128, BK=32.
// EPI: 1 = +f32 residual, f32 out; 2 = gelu, bf16 out
//      3 = QKV split: seg0/1 -> q,k row-major bf16 [.][1024]; seg2 -> v^T
// ---------------------------------------------------------------------------
template <int MT, int EPI>
__global__ __launch_bounds__(256) void gemm_bt(const ushort_t* __restrict__ A,
                                               const ushort_t* __restrict__ Bt,
                                               const float* __restrict__ b0,
                                               const float* __restrict__ b1,
                                               const float* __restrict__ b2,
                                               const float* __restrict__ res,
                                               void* __restrict__ out0,
                                               void* __restrict__ out1,
                                               void* __restrict__ out2,
                                               int M, int N, int K) {
    __shared__ ushort_t As[2][32 * MT * 32];
    __shared__ ushort_t Bs[2][128 * 32];
    const int t = threadIdx.x;
    const int wv = t >> 6, lane = t & 63, lo = lane & 15, hi = lane >> 4;
    const int wr = wv >> 1, wc = wv & 1;
    const int swz8 = (hi ^ ((lo >> 1) & 3)) * 8;   // read-side chunk swizzle

    // XCD-chunked swizzle (dispatch id d -> XCD d%8; give each XCD a
    // contiguous chunk of the x-major tile order = complete row-panels)
    const int nwg = gridDim.x * gridDim.y;
    const int id = blockIdx.y * gridDim.x + blockIdx.x;
    const int swz = (id & 7) * (nwg >> 3) + (id >> 3);
    const int nb = swz % gridDim.x, mb = swz / gridDim.x;

    f32x4 acc[MT][4];
#pragma unroll
    for (int i = 0; i < MT; ++i)
#pragma unroll
        for (int j = 0; j < 4; ++j) acc[i][j] = (f32x4){0.f, 0.f, 0.f, 0.f};

    auto STAGE = [&](int bf, int k0) {
#pragma unroll
        for (int i = 0; i < MT / 2; ++i) {
            int c = i * 256 + t;
            int row = c >> 2, kc = c & 3;
            int kof = (kc ^ ((row >> 1) & 3)) * 8;   // pre-swizzled source chunk
            async16((char*)&As[bf][0] + (size_t)(i * 256 + wv * 64) * 16,
                    A + (size_t)(mb * 32 * MT + row) * K + k0 + kof);
        }
#pragma unroll
        for (int i = 0; i < 2; ++i) {
            int c = i * 256 + t;
            int row = c >> 2, kc = c & 3;
            int kof = (kc ^ ((row >> 1) & 3)) * 8;
            async16((char*)&Bs[bf][0] + (size_t)(i * 256 + wv * 64) * 16,
                    Bt + (size_t)(nb * 128 + row) * K + k0 + kof);
        }
    };

    STAGE(0, 0);
    __syncthreads();

    const int NI = K >> 5;
    int bf = 0;
    for (int ki = 0; ki < NI; ++ki) {
        if (ki + 1 < NI) STAGE(bf ^ 1, (ki + 1) << 5);

        short8 af[MT], bfr[4];
#pragma unroll
        for (int mi = 0; mi < MT; ++mi)
            af[mi] = *(const short8*)(&As[bf][0] + (wr * 16 * MT + mi * 16 + lo) * 32 + swz8);
#pragma unroll
        for (int ni = 0; ni < 4; ++ni)
            bfr[ni] = *(const short8*)(&Bs[bf][0] + (wc * 64 + ni * 16 + lo) * 32 + swz8);
#pragma unroll
        for (int mi = 0; mi < MT; ++mi)
#pragma unroll
            for (int ni = 0; ni < 4; ++ni)
                acc[mi][ni] = __builtin_amdgcn_mfma_f32_16x16x32_bf16(
                    af[mi], bfr[ni], acc[mi][ni], 0, 0, 0);

        __syncthreads();   // drains vmcnt(0)+lgkm(0) AFTER compute; one barrier/iter
        bf ^= 1;
    }

#pragma unroll
    for (int ni = 0; ni < 4; ++ni) {
        int n = nb * 128 + wc * 64 + ni * 16 + lo;
        float bn;
        ushort_t* obf = nullptr;
        int coln = n, seg = 0;
        if (EPI == 3) {
            seg = n >> 10; coln = n & 1023;
            bn = (seg == 0 ? b0 : seg == 1 ? b1 : b2)[coln];
            obf = (ushort_t*)(seg == 0 ? out0 : out1);
        } else {
            bn = b0[n];
        }
#pragma unroll
        for (int mi = 0; mi < MT; ++mi) {
            if (EPI == 3 && seg == 2) {
                int m0 = mb * 32 * MT + wr * 16 * MT + mi * 16 + 4 * hi;
                ushort4 pk;
                pk.x = f2bf(acc[mi][ni][0] + bn);
                pk.y = f2bf(acc[mi][ni][1] + bn);
                pk.z = f2bf(acc[mi][ni][2] + bn);
                pk.w = f2bf(acc[mi][ni][3] + bn);
                *(ushort4*)((ushort_t*)out2 + (size_t)coln * M + m0) = pk;
            } else {
#pragma unroll
                for (int r = 0; r < 4; ++r) {
                    int m = mb * 32 * MT + wr * 16 * MT + mi * 16 + 4 * hi + r;
                    float v = acc[mi][ni][r] + bn;
                    if (EPI == 1) {
                        size_t idx = (size_t)m * N + n;
                        ((float*)out0)[idx] = v + res[idx];
                    } else if (EPI == 2) {
                        v = 0.5f * v * (1.0f + erff(v * 0.70710678118654752f));
                        ((ushort_t*)out0)[(size_t)m * N + n] = f2bf(v);
                    } else {
                        obf[(size_t)m * 1024 + coln] = f2bf(v);
                    }
                }
            }
        }
    }
}

// ---------------------------------------------------------------------------
// Causal flash attention: 64-row q-tiles, grid 1024 (32 qt x 32 bh),
// longest strips dispatched first; 4 blocks/CU (LDS = 40960).
// ---------------------------------------------------------------------------
__global__ __launch_bounds__(256) void attn_kernel(const ushort_t* __restrict__ q,
                                                   const ushort_t* __restrict__ k,
                                                   const ushort_t* __restrict__ vt,
                                                   ushort_t* __restrict__ ctx) {
    __shared__ ushort_t Ks[2][64 * 64];   // [buf][key][d], col-chunk swizzled
    __shared__ ushort_t VTs[2][64 * 64];  // [buf][d][key], col-chunk swizzled
    __shared__ ushort_t Ps[4][16 * 64];   // [wave][qrow][key], XOR-swizzled chunks

    const int t = threadIdx.x;
    const int wv = t >> 6, lane = t & 63, lo = lane & 15, hi = lane >> 4;
    const int id = blockIdx.x;             // 1024
    const int qt = 31 - (id >> 5);         // longest-first
    const int bh = id & 31, b = bh >> 4, h = bh & 15;
    const int q0 = qt * 64;
    const size_t headoff = (size_t)h * 64;
    const size_t rowbase = (size_t)b * T_ * 1024;
    const ushort_t* vbase = vt + headoff * (size_t)M_ + (size_t)b * T_;

    short8 qf[2];
    {
        const ushort_t* qp = q + rowbase + (size_t)(q0 + wv * 16 + lo) * 1024 + headoff;
        qf[0] = *(const short8*)(qp + hi * 8);
        qf[1] = *(const short8*)(qp + 32 + hi * 8);
    }

    float m_r = -1e30f, l_r = 0.f;
    f32x4 o_acc[4];
#pragma unroll
    for (int dt = 0; dt < 4; ++dt) o_acc[dt] = (f32x4){0.f, 0.f, 0.f, 0.f};

    const float SC = 0.18033688011112042f;  // 0.125 * log2(e)
    const f32x4 NEG4 = (f32x4){-1e30f, -1e30f, -1e30f, -1e30f};

    auto stage = [&](int bb, int kt) {
        const int k0s = kt * 64;
#pragma unroll
        for (int i = 0; i < 2; ++i) {
            int c = i * 256 + t;
            int row = c >> 3, c8 = c & 7;
            int gsw = c8 ^ (row & 7);
            async16((char*)&Ks[bb][0] + (size_t)(i * 256 + wv * 64) * 16,
                    k + rowbase + (size_t)(k0s + row) * 1024 + headoff + gsw * 8);
            async16((char*)&VTs[bb][0] + (size_t)(i * 256 + wv * 64) * 16,
                    vbase + (size_t)row * M_ + k0s + gsw * 8);
        }
    };

    ushort_t* Pw = Ps[wv];
    const int psw = lo & 7;

    stage(0, 0);
    for (int kt = 0; kt <= qt; ++kt) {
        const int bb = kt & 1;
        const int k0 = kt * 64;
        __syncthreads();
        if (kt < qt) stage(bb ^ 1, kt + 1);

        const int diff = q0 + wv * 16 - k0;   // >= 0 always (kt <= qt)
        const int cmax = diff >= 48 ? 3 : (diff >> 4);

        f32x4 sacc[4];
#pragma unroll
        for (int kt16 = 0; kt16 < 4; ++kt16) {
            if (kt16 <= cmax) {
                int row = kt16 * 16 + lo, sw = row & 7;
                short8 kf0 = *(const short8*)(&Ks[bb][0] + row * 64 + (hi ^ sw) * 8);
                short8 kf1 = *(const short8*)(&Ks[bb][0] + row * 64 + ((4 + hi) ^ sw) * 8);
                f32x4 z = (f32x4){0.f, 0.f, 0.f, 0.f};
                z = __builtin_amdgcn_mfma_f32_16x16x32_bf16(kf0, qf[0], z, 0, 0, 0);
                z = __builtin_amdgcn_mfma_f32_16x16x32_bf16(kf1, qf[1], z, 0, 0, 0);
#pragma unroll
                for (int r = 0; r < 4; ++r) sacc[kt16][r] = z[r] * SC;
            } else {
                sacc[kt16] = NEG4;
            }
        }
        if (diff < 64) {  // diagonal subtile: element mask key > qrow
            const int qrow = diff + lo;
#pragma unroll
            for (int r = 0; r < 4; ++r) {
                int key = cmax * 16 + 4 * hi + r;
                if (key > qrow) sacc[cmax][r] = -1e30f;
            }
        }

        // ---- online softmax (rows = lo), packed P spill ----
        float mx = -1e30f;
#pragma unroll
        for (int kt16 = 0; kt16 < 4; ++kt16)
#pragma unroll
            for (int r = 0; r < 4; ++r) mx = fmaxf(mx, sacc[kt16][r]);
        mx = fmaxf(mx, __shfl_xor(mx, 16, 64));
        mx = fmaxf(mx, __shfl_xor(mx, 32, 64));
        float mnew = fmaxf(m_r, mx);
        float alpha = fexp2(m_r - mnew);
        m_r = mnew;
        float rs = 0.f;
#pragma unroll
        for (int kt16 = 0; kt16 < 4; ++kt16) {
            float p0 = fexp2(sacc[kt16][0] - mnew);
            float p1 = fexp2(sacc[kt16][1] - mnew);
            float p2 = fexp2(sacc[kt16][2] - mnew);
            float p3 = fexp2(sacc[kt16][3] - mnew);
            rs += p0 + p1 + p2 + p3;
            ushort4 pk;
            pk.x = f2bf(p0); pk.y = f2bf(p1); pk.z = f2bf(p2); pk.w = f2bf(p3);
            // key s = kt16*16 + 4*hi + r -> chunk 2*kt16 + (hi>>1), offset 4*(hi&1)
            *(ushort4*)(Pw + lo * 64 + (((2 * kt16 + (hi >> 1)) ^ psw) << 3) + 4 * (hi & 1)) = pk;
        }
        rs += __shfl_xor(rs, 16, 64);
        rs += __shfl_xor(rs, 32, 64);
        l_r = l_r * alpha + rs;
#pragma unroll
        for (int r = 0; r < 4; ++r) {
            float ab = __shfl(alpha, 4 * hi + r, 64);
#pragma unroll
            for (int dt = 0; dt < 4; ++dt) o_acc[dt][r] *= ab;
        }

        // ---- read P fragments back (same-wave LDS, in-order) ----
        short8 pf0 = *(const short8*)(Pw + lo * 64 + ((hi ^ psw) << 3));
        short8 pf1 = *(const short8*)(Pw + lo * 64 + (((4 + hi) ^ psw) << 3));

        // ---- PV ----
#pragma unroll
        for (int dt = 0; dt < 4; ++dt) {
            int row = dt * 16 + lo, sw = row & 7;
            short8 vf0 = *(const short8*)(&VTs[bb][0] + row * 64 + (hi ^ sw) * 8);
            short8 vf1 = *(const short8*)(&VTs[bb][0] + row * 64 + ((4 + hi) ^ sw) * 8);
            o_acc[dt] = __builtin_amdgcn_mfma_f32_16x16x32_bf16(pf0, vf0, o_acc[dt], 0, 0, 0);
            o_acc[dt] = __builtin_amdgcn_mfma_f32_16x16x32_bf16(pf1, vf1, o_acc[dt], 0, 0, 0);
        }
    }

#pragma unroll
    for (int r = 0; r < 4; ++r) {
        float lb = __shfl(l_r, 4 * hi + r, 64);
        float inv = 1.0f / lb;
        size_t row = rowbase + (size_t)(q0 + wv * 16 + 4 * hi + r) * 1024 + headoff;
#pragma unroll
        for (int dt = 0; dt < 4; ++dt)
            ctx[row + dt * 16 + lo] = f2bf(o_acc[dt][r] * inv);
    }
}

// ---------------------------------------------------------------------------
extern "C" void kernel_launch(void* const* d_in, const int* in_sizes, int n_in,
                              void* d_out, int out_size, void* d_ws, size_t ws_size,
                              hipStream_t stream) {
    (void)in_sizes; (void)n_in; (void)out_size; (void)ws_size;
    const float* x    = (const float*)d_in[0];
    const float* Wq   = (const float*)d_in[1];
    const float* bq   = (const float*)d_in[2];
    const float* Wk   = (const float*)d_in[3];
    const float* bk   = (const float*)d_in[4];
    const float* Wv   = (const float*)d_in[5];
    const float* bv   = (const float*)d_in[6];
    const float* Wo   = (const float*)d_in[7];
    const float* bo   = (const float*)d_in[8];
    const float* W1   = (const float*)d_in[9];
    const float* b1   = (const float*)d_in[10];
    const float* W2   = (const float*)d_in[11];
    const float* b2   = (const float*)d_in[12];
    const float* ln1s = (const float*)d_in[13];
    const float* ln1b = (const float*)d_in[14];
    const float* ln2s = (const float*)d_in[15];
    const float* ln2b = (const float*)d_in[16];

    char* ws = (char*)d_ws;
    const size_t MB = 1024 * 1024;
    ushort_t* wqkv = (ushort_t*)(ws + 0 * MB);   // wtq|wtk|wtv contiguous [3072][1024]
    ushort_t* wtq  = (ushort_t*)(ws + 0 * MB);
    ushort_t* wtk  = (ushort_t*)(ws + 2 * MB);
    ushort_t* wtv  = (ushort_t*)(ws + 4 * MB);
    ushort_t* wto  = (ushort_t*)(ws + 6 * MB);
    ushort_t* wt1  = (ushort_t*)(ws + 8 * MB);   // 8MB (4096x1024)
    ushort_t* wt2  = (ushort_t*)(ws + 16 * MB);  // 8MB (1024x4096)
    ushort_t* hbuf = (ushort_t*)(ws + 24 * MB);  // 8MB
    ushort_t* qb_  = (ushort_t*)(ws + 32 * MB);  // 8MB
    ushort_t* kb_  = (ushort_t*)(ws + 40 * MB);  // 8MB
    ushort_t* ctx  = (ushort_t*)(ws + 56 * MB);  // 8MB
    ushort_t* hid  = (ushort_t*)(ws + 32 * MB);  // 32MB, reuses q/k/ctx post-attn
    float*    x1   = (float*)(ws + 64 * MB);     // 16MB fp32 (written after attn)
    ushort_t* vtb  = (ushort_t*)(ws + 64 * MB);  // 8MB [1024][4096], dead after attn

    transpose_all_k<<<12288, dim3(32, 8), 0, stream>>>(Wq, Wk, Wv, Wo, W1, W2,
                                                       wtq, wtk, wtv, wto, wt1, wt2);

    ln_kernel<<<4096, 256, 0, stream>>>(x, ln1s, ln1b, hbuf);

    // fused QKV (dbuf m97 + swizzle); seg2 writes v^T into vtb [1024][4096]
    gemm_bt<4, 3><<<dim3(24, 32), 256, 0, stream>>>(hbuf, wqkv, bq, bk, bv, nullptr,
                                                    qb_, kb_, vtb, 4096, 3072, 1024);

    attn_kernel<<<1024, 256, 0, stream>>>(qb_, kb_, vtb, ctx);

    // Wo projection: x1 = x + bo + ctx @ Wo^T
    gemm_bt<2, 1><<<dim3(8, 64), 256, 0, stream>>>(ctx, wto, bo, nullptr, nullptr, x,
                                                   x1, nullptr, nullptr, 4096, 1024, 1024);

    ln_kernel<<<4096, 256, 0, stream>>>(x1, ln2s, ln2b, hbuf);

    // FF1 (dbuf m97 + swizzle, gelu epilogue)
    gemm_bt<4, 2><<<dim3(32, 32), 256, 0, stream>>>(hbuf, wt1, b1, nullptr, nullptr, nullptr,
                                                    hid, nullptr, nullptr, 4096, 4096, 1024);

    // FF2: d_out = x1 + b2 + hid @ W2^T
    gemm_bt<2, 1><<<dim3(8, 64), 256, 0, stream>>>(hid, wt2, b2, nullptr, nullptr, x1,
                                                   (float*)d_out, nullptr, nullptr, 4096, 1024, 4096);
}